// Round 1
// baseline (2917.299 us; speedup 1.0000x reference)
//
#include <hip/hip_runtime.h>

#define D 128

__global__ __launch_bounds__(256) void k_degrees(
        const int* __restrict__ src, const int* __restrict__ dst,
        int* __restrict__ degO, int* __restrict__ degI, int nE) {
    int i = blockIdx.x * blockDim.x + threadIdx.x;
    if (i < nE) {
        atomicAdd(&degO[src[i]], 1);
        atomicAdd(&degI[dst[i]], 1);
    }
}

// agg[dst] += heat[src] * rsqrt(max(degO[src],1))   (agg = d_out, pre-zeroed)
__global__ __launch_bounds__(256) void k_scatter(
        const float* __restrict__ heat, const int* __restrict__ src,
        const int* __restrict__ dst, const int* __restrict__ degO,
        float* __restrict__ agg, int nE) {
    int e = blockIdx.x * 8 + (threadIdx.x >> 5);
    if (e >= nE) return;
    int l = threadIdx.x & 31;
    int s = src[e], d = dst[e];
    float sc = rsqrtf((float)max(degO[s], 1));
    const float4 v = *reinterpret_cast<const float4*>(heat + (size_t)s * D + (l << 2));
    float* base = agg + (size_t)d * D + (l << 2);
    atomicAdd(base + 0, v.x * sc);
    atomicAdd(base + 1, v.y * sc);
    atomicAdd(base + 2, v.z * sc);
    atomicAdd(base + 3, v.w * sc);
}

// h = prelu( (agg * rsqrt(deg_in)) @ W + b, a1 );  accumulate per-feature sum/sumsq
#define TN 32
__global__ __launch_bounds__(256) void k_gemm(
        const float* __restrict__ agg, const float* __restrict__ W,
        const float* __restrict__ b, const int* __restrict__ degI,
        const float* __restrict__ a1,
        float* __restrict__ h, float* __restrict__ sums, float* __restrict__ sumsq,
        int nN) {
    __shared__ float sA[TN][D + 4];
    __shared__ float r1[128], r2[128];
    int t = threadIdx.x;
    int n0 = blockIdx.x * TN;
    #pragma unroll
    for (int i = 0; i < 4; ++i) {
        int idx = t + i * 256;          // float4 slot 0..1023
        int n = idx >> 5;
        int c = (idx & 31) << 2;
        int node = n0 + n;
        float4 v = make_float4(0.f, 0.f, 0.f, 0.f);
        float sc = 0.f;
        if (node < nN) {
            v = *reinterpret_cast<const float4*>(agg + (size_t)node * D + c);
            sc = rsqrtf((float)max(degI[node], 1));
        }
        sA[n][c + 0] = v.x * sc;
        sA[n][c + 1] = v.y * sc;
        sA[n][c + 2] = v.z * sc;
        sA[n][c + 3] = v.w * sc;
    }
    __syncthreads();
    int f = t & 127;
    int sub = t >> 7;                   // 0 or 1; uniform per wave -> LDS broadcast
    float acc[16];
    #pragma unroll
    for (int i = 0; i < 16; ++i) acc[i] = 0.f;
    for (int k0 = 0; k0 < D; k0 += 4) {
        float wv0 = W[(k0 + 0) * D + f];
        float wv1 = W[(k0 + 1) * D + f];
        float wv2 = W[(k0 + 2) * D + f];
        float wv3 = W[(k0 + 3) * D + f];
        #pragma unroll
        for (int i = 0; i < 16; ++i) {
            float4 av = *reinterpret_cast<const float4*>(&sA[sub + i * 2][k0]);
            acc[i] += av.x * wv0 + av.y * wv1 + av.z * wv2 + av.w * wv3;
        }
    }
    float alpha = a1[0];
    float bias = b[f];
    float s1 = 0.f, s2 = 0.f;
    #pragma unroll
    for (int i = 0; i < 16; ++i) {
        int node = n0 + sub + i * 2;
        if (node < nN) {
            float v = acc[i] + bias;
            v = v > 0.f ? v : alpha * v;
            h[(size_t)node * D + f] = v;
            s1 += v;
            s2 += v * v;
        }
    }
    if (sub == 1) { r1[f] = s1; r2[f] = s2; }
    __syncthreads();
    if (sub == 0) {
        int slot = blockIdx.x & 15;     // spread contention 16-way
        atomicAdd(&sums[slot * D + f], s1 + r1[f]);
        atomicAdd(&sumsq[slot * D + f], s2 + r2[f]);
    }
}

__global__ void k_finalize(
        const float* __restrict__ sums, const float* __restrict__ sumsq,
        const float* __restrict__ gamma, const float* __restrict__ beta,
        float* __restrict__ stats, int nN) {
    int f = threadIdx.x;                // 128 threads
    float s1 = 0.f, s2 = 0.f;
    #pragma unroll
    for (int i = 0; i < 16; ++i) { s1 += sums[i * D + f]; s2 += sumsq[i * D + f]; }
    float inv_n = 1.0f / (float)nN;
    float mean = s1 * inv_n;
    float var = s2 * inv_n - mean * mean;
    float inv = rsqrtf(var + 1e-5f);
    float sc = gamma[f] * inv;
    stats[f] = sc;
    stats[D + f] = beta[f] - mean * sc;
}

__global__ __launch_bounds__(256) void k_apply(
        const float* __restrict__ h, const float* __restrict__ stats,
        const float* __restrict__ a2, float* __restrict__ out, int total4) {
    int i = blockIdx.x * 256 + threadIdx.x;
    if (i >= total4) return;
    float alpha = a2[0];
    int c = (i & 31) << 2;
    float4 v = *reinterpret_cast<const float4*>(h + (size_t)i * 4);
    float4 sc = *reinterpret_cast<const float4*>(stats + c);
    float4 sh = *reinterpret_cast<const float4*>(stats + D + c);
    float4 r;
    r.x = v.x * sc.x + sh.x; r.x = r.x > 0.f ? r.x : alpha * r.x;
    r.y = v.y * sc.y + sh.y; r.y = r.y > 0.f ? r.y : alpha * r.y;
    r.z = v.z * sc.z + sh.z; r.z = r.z > 0.f ? r.z : alpha * r.z;
    r.w = v.w * sc.w + sh.w; r.w = r.w > 0.f ? r.w : alpha * r.w;
    *reinterpret_cast<float4*>(out + (size_t)i * 4) = r;
}

extern "C" void kernel_launch(void* const* d_in, const int* in_sizes, int n_in,
                              void* d_out, int out_size, void* d_ws, size_t ws_size,
                              hipStream_t stream) {
    const float* heat  = (const float*)d_in[0];
    const float* W     = (const float*)d_in[1];
    const float* b     = (const float*)d_in[2];
    const float* a1    = (const float*)d_in[3];
    const float* gamma = (const float*)d_in[4];
    const float* beta  = (const float*)d_in[5];
    const float* a2    = (const float*)d_in[6];
    const int*   src   = (const int*)d_in[7];
    const int*   dst   = (const int*)d_in[8];

    const int nN = in_sizes[0] / D;
    const int nE = in_sizes[7];

    char* ws = (char*)d_ws;
    int*   degO  = (int*)(ws + 0);                 // nN ints
    int*   degI  = (int*)(ws + 400384);            // nN ints
    float* sums  = (float*)(ws + 800768);          // 16*128 f
    float* sumsq = (float*)(ws + 808960);          // 16*128 f
    float* stats = (float*)(ws + 817152);          // 256 f
    float* h     = (float*)(ws + 1048576);         // nN*128 f (51.2 MB)
    float* agg   = (float*)d_out;                  // reuse output as accumulator

    // zero degrees + stat accumulators (one contiguous region) and agg
    hipMemsetAsync(ws, 0, 818176, stream);
    hipMemsetAsync(agg, 0, (size_t)nN * D * sizeof(float), stream);

    k_degrees<<<(nE + 255) / 256, 256, 0, stream>>>(src, dst, degO, degI, nE);
    k_scatter<<<(nE + 7) / 8, 256, 0, stream>>>(heat, src, dst, degO, agg, nE);
    k_gemm<<<(nN + TN - 1) / TN, 256, 0, stream>>>(agg, W, b, degI, a1, h, sums, sumsq, nN);
    k_finalize<<<1, 128, 0, stream>>>(sums, sumsq, gamma, beta, stats, nN);
    k_apply<<<(nN * (D / 4) + 255) / 256, 256, 0, stream>>>(h, stats, a2, (float*)d_out, nN * (D / 4));
}

// Round 2
// 713.400 us; speedup vs baseline: 4.0893x; 4.0893x over previous
//
#include <hip/hip_runtime.h>

#define D 128

__global__ __launch_bounds__(256) void k_degrees(
        const int* __restrict__ src, const int* __restrict__ dst,
        int* __restrict__ degO, int* __restrict__ degI, int nE) {
    int i = blockIdx.x * blockDim.x + threadIdx.x;
    if (i < nE) {
        atomicAdd(&degO[src[i]], 1);
        atomicAdd(&degI[dst[i]], 1);
    }
}

__global__ __launch_bounds__(256) void k_prep(
        const int* __restrict__ degO, float* __restrict__ rsO, int nN) {
    int i = blockIdx.x * 256 + threadIdx.x;
    if (i < nN) rsO[i] = rsqrtf((float)max(degO[i], 1));
}

// single-block exclusive scan of degI -> offs, cursor
__global__ __launch_bounds__(1024) void k_scan(
        const int* __restrict__ degI, int* __restrict__ offs,
        int* __restrict__ cursor, int nN) {
    __shared__ int part[1024];
    int t = threadIdx.x;
    int C = (nN + 1023) / 1024;
    int lo = t * C, hi = min(lo + C, nN);
    int s = 0;
    for (int i = lo; i < hi; ++i) s += degI[i];
    part[t] = s;
    __syncthreads();
    for (int off = 1; off < 1024; off <<= 1) {
        int v = (t >= off) ? part[t - off] : 0;
        __syncthreads();
        part[t] += v;
        __syncthreads();
    }
    int base = (t == 0) ? 0 : part[t - 1];
    for (int i = lo; i < hi; ++i) {
        offs[i] = base;
        cursor[i] = base;
        base += degI[i];
    }
}

__global__ __launch_bounds__(256) void k_fill(
        const int* __restrict__ src, const int* __restrict__ dst,
        int* __restrict__ cursor, int* __restrict__ elist, int nE) {
    int i = blockIdx.x * 256 + threadIdx.x;
    if (i < nE) {
        int d = dst[i];
        int pos = atomicAdd(&cursor[d], 1);
        elist[pos] = src[i];
    }
}

// one wave per node: agg[node] = sum over CSR segment of heat[s] * rsO[s]
__global__ __launch_bounds__(256) void k_gather(
        const float* __restrict__ heat, const int* __restrict__ elist,
        const int* __restrict__ offs, const int* __restrict__ degI,
        const float* __restrict__ rsO, float* __restrict__ agg, int nN) {
    int node = blockIdx.x * 4 + (threadIdx.x >> 6);
    if (node >= nN) return;
    int l = threadIdx.x & 63;
    int start = offs[node];
    int end = start + degI[node];
    float ax = 0.f, ay = 0.f;
    for (int jb = start; jb < end; jb += 64) {
        int cnt = min(64, end - jb);
        int sl = (l < cnt) ? elist[jb + l] : 0;
        float scl = (l < cnt) ? rsO[sl] : 0.f;
        for (int k = 0; k < cnt; ++k) {
            int s = __shfl(sl, k);
            float sc = __shfl(scl, k);
            const float2 v = *reinterpret_cast<const float2*>(heat + (size_t)s * D + (l << 1));
            ax += v.x * sc;
            ay += v.y * sc;
        }
    }
    float2 r = make_float2(ax, ay);
    *reinterpret_cast<float2*>(agg + (size_t)node * D + (l << 1)) = r;
}

// h = prelu( (agg * rsqrt(deg_in)) @ W + b, a1 );  accumulate per-feature sum/sumsq
#define TN 32
__global__ __launch_bounds__(256) void k_gemm(
        const float* __restrict__ agg, const float* __restrict__ W,
        const float* __restrict__ b, const int* __restrict__ degI,
        const float* __restrict__ a1,
        float* __restrict__ h, float* __restrict__ sums, float* __restrict__ sumsq,
        int nN) {
    __shared__ float sA[TN][D + 4];
    __shared__ float r1[128], r2[128];
    int t = threadIdx.x;
    int n0 = blockIdx.x * TN;
    #pragma unroll
    for (int i = 0; i < 4; ++i) {
        int idx = t + i * 256;
        int n = idx >> 5;
        int c = (idx & 31) << 2;
        int node = n0 + n;
        float4 v = make_float4(0.f, 0.f, 0.f, 0.f);
        float sc = 0.f;
        if (node < nN) {
            v = *reinterpret_cast<const float4*>(agg + (size_t)node * D + c);
            sc = rsqrtf((float)max(degI[node], 1));
        }
        sA[n][c + 0] = v.x * sc;
        sA[n][c + 1] = v.y * sc;
        sA[n][c + 2] = v.z * sc;
        sA[n][c + 3] = v.w * sc;
    }
    __syncthreads();
    int f = t & 127;
    int sub = t >> 7;
    float acc[16];
    #pragma unroll
    for (int i = 0; i < 16; ++i) acc[i] = 0.f;
    for (int k0 = 0; k0 < D; k0 += 4) {
        float wv0 = W[(k0 + 0) * D + f];
        float wv1 = W[(k0 + 1) * D + f];
        float wv2 = W[(k0 + 2) * D + f];
        float wv3 = W[(k0 + 3) * D + f];
        #pragma unroll
        for (int i = 0; i < 16; ++i) {
            float4 av = *reinterpret_cast<const float4*>(&sA[sub + i * 2][k0]);
            acc[i] += av.x * wv0 + av.y * wv1 + av.z * wv2 + av.w * wv3;
        }
    }
    float alpha = a1[0];
    float bias = b[f];
    float s1 = 0.f, s2 = 0.f;
    #pragma unroll
    for (int i = 0; i < 16; ++i) {
        int node = n0 + sub + i * 2;
        if (node < nN) {
            float v = acc[i] + bias;
            v = v > 0.f ? v : alpha * v;
            h[(size_t)node * D + f] = v;
            s1 += v;
            s2 += v * v;
        }
    }
    if (sub == 1) { r1[f] = s1; r2[f] = s2; }
    __syncthreads();
    if (sub == 0) {
        int slot = blockIdx.x & 15;
        atomicAdd(&sums[slot * D + f], s1 + r1[f]);
        atomicAdd(&sumsq[slot * D + f], s2 + r2[f]);
    }
}

__global__ void k_finalize(
        const float* __restrict__ sums, const float* __restrict__ sumsq,
        const float* __restrict__ gamma, const float* __restrict__ beta,
        float* __restrict__ stats, int nN) {
    int f = threadIdx.x;
    float s1 = 0.f, s2 = 0.f;
    #pragma unroll
    for (int i = 0; i < 16; ++i) { s1 += sums[i * D + f]; s2 += sumsq[i * D + f]; }
    float inv_n = 1.0f / (float)nN;
    float mean = s1 * inv_n;
    float var = s2 * inv_n - mean * mean;
    float inv = rsqrtf(var + 1e-5f);
    float sc = gamma[f] * inv;
    stats[f] = sc;
    stats[D + f] = beta[f] - mean * sc;
}

// in-place BN + PReLU on d_out
__global__ __launch_bounds__(256) void k_apply(
        float* __restrict__ h, const float* __restrict__ stats,
        const float* __restrict__ a2, int total4) {
    int i = blockIdx.x * 256 + threadIdx.x;
    if (i >= total4) return;
    float alpha = a2[0];
    int c = (i & 31) << 2;
    float4 v = *reinterpret_cast<const float4*>(h + (size_t)i * 4);
    float4 sc = *reinterpret_cast<const float4*>(stats + c);
    float4 sh = *reinterpret_cast<const float4*>(stats + D + c);
    float4 r;
    r.x = v.x * sc.x + sh.x; r.x = r.x > 0.f ? r.x : alpha * r.x;
    r.y = v.y * sc.y + sh.y; r.y = r.y > 0.f ? r.y : alpha * r.y;
    r.z = v.z * sc.z + sh.z; r.z = r.z > 0.f ? r.z : alpha * r.z;
    r.w = v.w * sc.w + sh.w; r.w = r.w > 0.f ? r.w : alpha * r.w;
    *reinterpret_cast<float4*>(h + (size_t)i * 4) = r;
}

extern "C" void kernel_launch(void* const* d_in, const int* in_sizes, int n_in,
                              void* d_out, int out_size, void* d_ws, size_t ws_size,
                              hipStream_t stream) {
    const float* heat  = (const float*)d_in[0];
    const float* W     = (const float*)d_in[1];
    const float* b     = (const float*)d_in[2];
    const float* a1    = (const float*)d_in[3];
    const float* gamma = (const float*)d_in[4];
    const float* beta  = (const float*)d_in[5];
    const float* a2    = (const float*)d_in[6];
    const int*   src   = (const int*)d_in[7];
    const int*   dst   = (const int*)d_in[8];

    const int nN = in_sizes[0] / D;
    const int nE = in_sizes[7];

    char* ws = (char*)d_ws;
    int*   degO   = (int*)(ws + 0);            // nN
    int*   degI   = (int*)(ws + 400384);       // nN
    float* rsO    = (float*)(ws + 800768);     // nN
    int*   offs   = (int*)(ws + 1201152);      // nN
    int*   cursor = (int*)(ws + 1601536);      // nN
    float* sums   = (float*)(ws + 2001920);    // 16*128
    float* sumsq  = (float*)(ws + 2010112);    // 16*128
    float* stats  = (float*)(ws + 2018304);    // 256
    int*   elist  = (int*)(ws + 2097152);      // nE (6.4 MB)
    float* agg    = (float*)(ws + 8497152);    // nN*128 (51.2 MB)
    float* h      = (float*)d_out;             // output doubles as pre-BN buffer

    // zero degO, degI, sums, sumsq (covers rsO/offs/cursor harmlessly)
    hipMemsetAsync(ws, 0, 2019328, stream);

    k_degrees<<<(nE + 255) / 256, 256, 0, stream>>>(src, dst, degO, degI, nE);
    k_prep<<<(nN + 255) / 256, 256, 0, stream>>>(degO, rsO, nN);
    k_scan<<<1, 1024, 0, stream>>>(degI, offs, cursor, nN);
    k_fill<<<(nE + 255) / 256, 256, 0, stream>>>(src, dst, cursor, elist, nE);
    k_gather<<<(nN + 3) / 4, 256, 0, stream>>>(heat, elist, offs, degI, rsO, agg, nN);
    k_gemm<<<(nN + TN - 1) / TN, 256, 0, stream>>>(agg, W, b, degI, a1, h, sums, sumsq, nN);
    k_finalize<<<1, 128, 0, stream>>>(sums, sumsq, gamma, beta, stats, nN);
    k_apply<<<(nN * (D / 4) + 255) / 256, 256, 0, stream>>>(h, stats, a2, nN * (D / 4));
}

// Round 3
// 495.756 us; speedup vs baseline: 5.8845x; 1.4390x over previous
//
#include <hip/hip_runtime.h>

#define D 128

__global__ __launch_bounds__(256) void k_degrees(
        const int* __restrict__ src, const int* __restrict__ dst,
        int* __restrict__ degO, int* __restrict__ degI, int nE) {
    int i = blockIdx.x * blockDim.x + threadIdx.x;
    if (i < nE) {
        atomicAdd(&degO[src[i]], 1);
        atomicAdd(&degI[dst[i]], 1);
    }
}

__global__ __launch_bounds__(256) void k_prep(
        const int* __restrict__ degO, float* __restrict__ rsO, int nN) {
    int i = blockIdx.x * 256 + threadIdx.x;
    if (i < nN) rsO[i] = rsqrtf((float)max(degO[i], 1));
}

// --- multi-block exclusive scan of degI -> offs, cursor ---
__global__ __launch_bounds__(256) void k_blocksum(
        const int* __restrict__ degI, int* __restrict__ part, int nN) {
    __shared__ int red[256];
    int t = threadIdx.x;
    int i = blockIdx.x * 256 + t;
    red[t] = (i < nN) ? degI[i] : 0;
    __syncthreads();
    #pragma unroll
    for (int off = 128; off > 0; off >>= 1) {
        if (t < off) red[t] += red[t + off];
        __syncthreads();
    }
    if (t == 0) part[blockIdx.x] = red[0];
}

__global__ __launch_bounds__(1024) void k_scanpart(
        int* __restrict__ part, int nB) {
    __shared__ int sh[1024];
    int t = threadIdx.x;
    sh[t] = (t < nB) ? part[t] : 0;
    __syncthreads();
    for (int off = 1; off < 1024; off <<= 1) {
        int u = (t >= off) ? sh[t - off] : 0;
        __syncthreads();
        sh[t] += u;
        __syncthreads();
    }
    if (t < nB) part[t] = (t == 0) ? 0 : sh[t - 1];
}

__global__ __launch_bounds__(256) void k_offsets(
        const int* __restrict__ degI, const int* __restrict__ part,
        int* __restrict__ offs, int* __restrict__ cursor, int nN) {
    __shared__ int sh[256];
    int t = threadIdx.x;
    int i = blockIdx.x * 256 + t;
    sh[t] = (i < nN) ? degI[i] : 0;
    __syncthreads();
    for (int off = 1; off < 256; off <<= 1) {
        int u = (t >= off) ? sh[t - off] : 0;
        __syncthreads();
        sh[t] += u;
        __syncthreads();
    }
    if (i < nN) {
        int excl = part[blockIdx.x] + ((t == 0) ? 0 : sh[t - 1]);
        offs[i] = excl;
        cursor[i] = excl;
    }
}

__global__ __launch_bounds__(256) void k_fill(
        const int* __restrict__ src, const int* __restrict__ dst,
        int* __restrict__ cursor, int* __restrict__ elist, int nE) {
    int i = blockIdx.x * 256 + threadIdx.x;
    if (i < nE) {
        int d = dst[i];
        int pos = atomicAdd(&cursor[d], 1);
        elist[pos] = src[i];
    }
}

// one wave per node: agg[node] = sum over CSR segment of heat[s] * rsO[s]
__global__ __launch_bounds__(256) void k_gather(
        const float* __restrict__ heat, const int* __restrict__ elist,
        const int* __restrict__ offs, const int* __restrict__ degI,
        const float* __restrict__ rsO, float* __restrict__ agg, int nN) {
    int node = blockIdx.x * 4 + (threadIdx.x >> 6);
    if (node >= nN) return;
    int l = threadIdx.x & 63;
    int start = offs[node];
    int end = start + degI[node];
    float ax = 0.f, ay = 0.f;
    for (int jb = start; jb < end; jb += 64) {
        int cnt = min(64, end - jb);
        int sl = (l < cnt) ? elist[jb + l] : 0;
        float scl = (l < cnt) ? rsO[sl] : 0.f;
        for (int k = 0; k < cnt; ++k) {
            int s = __shfl(sl, k);
            float sc = __shfl(scl, k);
            const float2 v = *reinterpret_cast<const float2*>(heat + (size_t)s * D + (l << 1));
            ax += v.x * sc;
            ay += v.y * sc;
        }
    }
    float2 r = make_float2(ax, ay);
    *reinterpret_cast<float2*>(agg + (size_t)node * D + (l << 1)) = r;
}

// h = prelu( (agg * rsqrt(deg_in)) @ W + b, a1 );  accumulate per-feature sum/sumsq
#define TN 32
__global__ __launch_bounds__(256) void k_gemm(
        const float* __restrict__ agg, const float* __restrict__ W,
        const float* __restrict__ b, const int* __restrict__ degI,
        const float* __restrict__ a1,
        float* __restrict__ h, float* __restrict__ sums, float* __restrict__ sumsq,
        int nN) {
    __shared__ float sA[TN][D + 4];
    __shared__ float r1[128], r2[128];
    int t = threadIdx.x;
    int n0 = blockIdx.x * TN;
    #pragma unroll
    for (int i = 0; i < 4; ++i) {
        int idx = t + i * 256;
        int n = idx >> 5;
        int c = (idx & 31) << 2;
        int node = n0 + n;
        float4 v = make_float4(0.f, 0.f, 0.f, 0.f);
        float sc = 0.f;
        if (node < nN) {
            v = *reinterpret_cast<const float4*>(agg + (size_t)node * D + c);
            sc = rsqrtf((float)max(degI[node], 1));
        }
        sA[n][c + 0] = v.x * sc;
        sA[n][c + 1] = v.y * sc;
        sA[n][c + 2] = v.z * sc;
        sA[n][c + 3] = v.w * sc;
    }
    __syncthreads();
    int f = t & 127;
    int sub = t >> 7;
    float acc[16];
    #pragma unroll
    for (int i = 0; i < 16; ++i) acc[i] = 0.f;
    for (int k0 = 0; k0 < D; k0 += 4) {
        float wv0 = W[(k0 + 0) * D + f];
        float wv1 = W[(k0 + 1) * D + f];
        float wv2 = W[(k0 + 2) * D + f];
        float wv3 = W[(k0 + 3) * D + f];
        #pragma unroll
        for (int i = 0; i < 16; ++i) {
            float4 av = *reinterpret_cast<const float4*>(&sA[sub + i * 2][k0]);
            acc[i] += av.x * wv0 + av.y * wv1 + av.z * wv2 + av.w * wv3;
        }
    }
    float alpha = a1[0];
    float bias = b[f];
    float s1 = 0.f, s2 = 0.f;
    #pragma unroll
    for (int i = 0; i < 16; ++i) {
        int node = n0 + sub + i * 2;
        if (node < nN) {
            float v = acc[i] + bias;
            v = v > 0.f ? v : alpha * v;
            h[(size_t)node * D + f] = v;
            s1 += v;
            s2 += v * v;
        }
    }
    if (sub == 1) { r1[f] = s1; r2[f] = s2; }
    __syncthreads();
    if (sub == 0) {
        int slot = blockIdx.x & 15;
        atomicAdd(&sums[slot * D + f], s1 + r1[f]);
        atomicAdd(&sumsq[slot * D + f], s2 + r2[f]);
    }
}

__global__ void k_finalize(
        const float* __restrict__ sums, const float* __restrict__ sumsq,
        const float* __restrict__ gamma, const float* __restrict__ beta,
        float* __restrict__ stats, int nN) {
    int f = threadIdx.x;
    float s1 = 0.f, s2 = 0.f;
    #pragma unroll
    for (int i = 0; i < 16; ++i) { s1 += sums[i * D + f]; s2 += sumsq[i * D + f]; }
    float inv_n = 1.0f / (float)nN;
    float mean = s1 * inv_n;
    float var = s2 * inv_n - mean * mean;
    float inv = rsqrtf(var + 1e-5f);
    float sc = gamma[f] * inv;
    stats[f] = sc;
    stats[D + f] = beta[f] - mean * sc;
}

// in-place BN + PReLU on d_out
__global__ __launch_bounds__(256) void k_apply(
        float* __restrict__ h, const float* __restrict__ stats,
        const float* __restrict__ a2, int total4) {
    int i = blockIdx.x * 256 + threadIdx.x;
    if (i >= total4) return;
    float alpha = a2[0];
    int c = (i & 31) << 2;
    float4 v = *reinterpret_cast<const float4*>(h + (size_t)i * 4);
    float4 sc = *reinterpret_cast<const float4*>(stats + c);
    float4 sh = *reinterpret_cast<const float4*>(stats + D + c);
    float4 r;
    r.x = v.x * sc.x + sh.x; r.x = r.x > 0.f ? r.x : alpha * r.x;
    r.y = v.y * sc.y + sh.y; r.y = r.y > 0.f ? r.y : alpha * r.y;
    r.z = v.z * sc.z + sh.z; r.z = r.z > 0.f ? r.z : alpha * r.z;
    r.w = v.w * sc.w + sh.w; r.w = r.w > 0.f ? r.w : alpha * r.w;
    *reinterpret_cast<float4*>(h + (size_t)i * 4) = r;
}

extern "C" void kernel_launch(void* const* d_in, const int* in_sizes, int n_in,
                              void* d_out, int out_size, void* d_ws, size_t ws_size,
                              hipStream_t stream) {
    const float* heat  = (const float*)d_in[0];
    const float* W     = (const float*)d_in[1];
    const float* b     = (const float*)d_in[2];
    const float* a1    = (const float*)d_in[3];
    const float* gamma = (const float*)d_in[4];
    const float* beta  = (const float*)d_in[5];
    const float* a2    = (const float*)d_in[6];
    const int*   src   = (const int*)d_in[7];
    const int*   dst   = (const int*)d_in[8];

    const int nN = in_sizes[0] / D;
    const int nE = in_sizes[7];
    const int nB = (nN + 255) / 256;           // scan blocks (391)

    char* ws = (char*)d_ws;
    int*   degO   = (int*)(ws + 0);            // nN
    int*   degI   = (int*)(ws + 400384);       // nN
    float* rsO    = (float*)(ws + 800768);     // nN
    int*   offs   = (int*)(ws + 1201152);      // nN
    int*   cursor = (int*)(ws + 1601536);      // nN
    float* sums   = (float*)(ws + 2001920);    // 16*128
    float* sumsq  = (float*)(ws + 2010112);    // 16*128
    float* stats  = (float*)(ws + 2018304);    // 256
    int*   part   = (int*)(ws + 2019328);      // nB ints (<4KB)
    int*   elist  = (int*)(ws + 2097152);      // nE (6.4 MB)
    float* agg    = (float*)(ws + 8497152);    // nN*128 (51.2 MB)
    float* h      = (float*)d_out;             // output doubles as pre-BN buffer

    // zero degO, degI, sums, sumsq (covers other small buffers harmlessly)
    hipMemsetAsync(ws, 0, 2019328, stream);

    k_degrees<<<(nE + 255) / 256, 256, 0, stream>>>(src, dst, degO, degI, nE);
    k_prep<<<(nN + 255) / 256, 256, 0, stream>>>(degO, rsO, nN);
    k_blocksum<<<nB, 256, 0, stream>>>(degI, part, nN);
    k_scanpart<<<1, 1024, 0, stream>>>(part, nB);
    k_offsets<<<nB, 256, 0, stream>>>(degI, part, offs, cursor, nN);
    k_fill<<<(nE + 255) / 256, 256, 0, stream>>>(src, dst, cursor, elist, nE);
    k_gather<<<(nN + 3) / 4, 256, 0, stream>>>(heat, elist, offs, degI, rsO, agg, nN);
    k_gemm<<<(nN + TN - 1) / TN, 256, 0, stream>>>(agg, W, b, degI, a1, h, sums, sumsq, nN);
    k_finalize<<<1, 128, 0, stream>>>(sums, sumsq, gamma, beta, stats, nN);
    k_apply<<<(nN * (D / 4) + 255) / 256, 256, 0, stream>>>(h, stats, a2, nN * (D / 4));
}

// Round 4
// 339.167 us; speedup vs baseline: 8.6014x; 1.4617x over previous
//
#include <hip/hip_runtime.h>

#define D 128

__device__ __forceinline__ unsigned int f2bf(float x) {
    unsigned int u = __float_as_uint(x);
    return (u + 0x7FFFu + ((u >> 16) & 1u)) >> 16;   // RNE
}

// degO atomics + per-bucket dst histogram (bucket = dst>>8)
__global__ __launch_bounds__(256) void k_count(
        const int* __restrict__ src, const int* __restrict__ dst,
        int* __restrict__ degO, int* __restrict__ bcnt, int nE, int NB) {
    __shared__ int lh[512];
    int t = threadIdx.x;
    lh[t] = 0; lh[t + 256] = 0;
    __syncthreads();
    int base = blockIdx.x * 4096;
    #pragma unroll
    for (int i = 0; i < 16; ++i) {
        int e = base + i * 256 + t;
        if (e < nE) {
            atomicAdd(&degO[src[e]], 1);
            atomicAdd(&lh[dst[e] >> 8], 1);
        }
    }
    __syncthreads();
    for (int i = t; i < NB; i += 256)
        if (lh[i]) atomicAdd(&bcnt[i], lh[i]);
}

// heatS = bf16(heat * rsqrt(max(degO,1)))
__global__ __launch_bounds__(256) void k_prep2(
        const float* __restrict__ heat, const int* __restrict__ degO,
        unsigned short* __restrict__ heatS, int nN) {
    int i = blockIdx.x * 256 + threadIdx.x;
    if (i >= nN * 32) return;
    int node = i >> 5;
    int c4 = (i & 31) << 2;
    float4 v = *reinterpret_cast<const float4*>(heat + ((size_t)node << 7) + c4);
    float sc = rsqrtf((float)max(degO[node], 1));
    unsigned int b0 = f2bf(v.x * sc), b1 = f2bf(v.y * sc);
    unsigned int b2 = f2bf(v.z * sc), b3 = f2bf(v.w * sc);
    uint2 p = make_uint2(b0 | (b1 << 16), b2 | (b3 << 16));
    *reinterpret_cast<uint2*>(heatS + ((size_t)node << 7) + c4) = p;
}

// exclusive scan of bucket counts (NB <= 512), one block
__global__ __launch_bounds__(512) void k_bscan(
        const int* __restrict__ bcnt, int* __restrict__ bbase,
        int* __restrict__ bcur, int NB) {
    __shared__ int sh[512];
    int t = threadIdx.x;
    sh[t] = (t < NB) ? bcnt[t] : 0;
    __syncthreads();
    for (int off = 1; off < 512; off <<= 1) {
        int u = (t >= off) ? sh[t - off] : 0;
        __syncthreads();
        sh[t] += u;
        __syncthreads();
    }
    int excl = (t == 0) ? 0 : sh[t - 1];
    if (t < NB) { bbase[t] = excl; bcur[t] = excl; }
    if (t == 511) bbase[NB] = sh[511];
}

// bin (src,dst) pairs into bucket regions with block-chunked reservations
__global__ __launch_bounds__(256) void k_pairs(
        const int* __restrict__ src, const int* __restrict__ dst,
        int* __restrict__ bcur, uint2* __restrict__ pairs, int nE, int NB) {
    __shared__ int lh[512];
    __shared__ int lcur[512];
    int t = threadIdx.x;
    lh[t] = 0; lh[t + 256] = 0;
    __syncthreads();
    int base = blockIdx.x * 4096;
    #pragma unroll
    for (int i = 0; i < 16; ++i) {
        int e = base + i * 256 + t;
        if (e < nE) atomicAdd(&lh[dst[e] >> 8], 1);
    }
    __syncthreads();
    for (int i = t; i < NB; i += 256) {
        int c = lh[i];
        lcur[i] = c ? atomicAdd(&bcur[i], c) : 0;
    }
    __syncthreads();
    #pragma unroll
    for (int i = 0; i < 16; ++i) {
        int e = base + i * 256 + t;
        if (e < nE) {
            int s = src[e], d = dst[e];
            int pos = atomicAdd(&lcur[d >> 8], 1);
            pairs[pos] = make_uint2((unsigned)s, (unsigned)d);
        }
    }
}

// per bucket: per-node counts -> degI/offs, grouped elist
__global__ __launch_bounds__(256) void k_binD(
        const uint2* __restrict__ pairs, const int* __restrict__ bbase,
        int* __restrict__ degI, int* __restrict__ offs,
        int* __restrict__ elist, int nN) {
    __shared__ int c0[256], sh[256], lcur[256];
    int b = blockIdx.x, t = threadIdx.x;
    int p0 = bbase[b], p1 = bbase[b + 1];
    int n0 = b << 8;
    c0[t] = 0;
    __syncthreads();
    for (int j = p0 + t; j < p1; j += 256)
        atomicAdd(&c0[(int)pairs[j].y - n0], 1);
    __syncthreads();
    sh[t] = c0[t];
    __syncthreads();
    for (int off = 1; off < 256; off <<= 1) {
        int u = (t >= off) ? sh[t - off] : 0;
        __syncthreads();
        sh[t] += u;
        __syncthreads();
    }
    int excl = (t == 0) ? 0 : sh[t - 1];
    int node = n0 + t;
    if (node < nN) { degI[node] = c0[t]; offs[node] = p0 + excl; }
    lcur[t] = p0 + excl;
    __syncthreads();
    for (int j = p0 + t; j < p1; j += 256) {
        uint2 pr = pairs[j];
        int pos = atomicAdd(&lcur[(int)pr.y - n0], 1);
        elist[pos] = (int)pr.x;
    }
}

// one wave per node: agg[node] = sum of pre-scaled bf16 rows of neighbors
__global__ __launch_bounds__(256) void k_gather(
        const unsigned short* __restrict__ heatS, const int* __restrict__ elist,
        const int* __restrict__ offs, const int* __restrict__ degI,
        float* __restrict__ agg, int nN) {
    int node = blockIdx.x * 4 + (threadIdx.x >> 6);
    if (node >= nN) return;
    int l = threadIdx.x & 63;
    int start = offs[node];
    int end = start + degI[node];
    float ax = 0.f, ay = 0.f;
    for (int jb = start; jb < end; jb += 64) {
        int cnt = min(64, end - jb);
        int sl = (l < cnt) ? elist[jb + l] : 0;
        for (int k = 0; k < cnt; ++k) {
            int s = __shfl(sl, k);
            unsigned int p = *reinterpret_cast<const unsigned int*>(
                heatS + ((size_t)s << 7) + (l << 1));
            ax += __uint_as_float(p << 16);
            ay += __uint_as_float(p & 0xFFFF0000u);
        }
    }
    *reinterpret_cast<float2*>(agg + ((size_t)node << 7) + (l << 1)) = make_float2(ax, ay);
}

// h = prelu( (agg * rsqrt(deg_in)) @ W + b, a1 );  in-place on d_out
#define TN 32
__global__ __launch_bounds__(256) void k_gemm(
        float* __restrict__ agg, const float* __restrict__ W,
        const float* __restrict__ b, const int* __restrict__ degI,
        const float* __restrict__ a1,
        float* __restrict__ sums, float* __restrict__ sumsq, int nN) {
    __shared__ float sA[TN][D + 4];
    __shared__ float r1[128], r2[128];
    int t = threadIdx.x;
    int n0 = blockIdx.x * TN;
    #pragma unroll
    for (int i = 0; i < 4; ++i) {
        int idx = t + i * 256;
        int n = idx >> 5;
        int c = (idx & 31) << 2;
        int node = n0 + n;
        float4 v = make_float4(0.f, 0.f, 0.f, 0.f);
        float sc = 0.f;
        if (node < nN) {
            v = *reinterpret_cast<const float4*>(agg + (size_t)node * D + c);
            sc = rsqrtf((float)max(degI[node], 1));
        }
        sA[n][c + 0] = v.x * sc;
        sA[n][c + 1] = v.y * sc;
        sA[n][c + 2] = v.z * sc;
        sA[n][c + 3] = v.w * sc;
    }
    __syncthreads();
    int f = t & 127;
    int sub = t >> 7;
    float acc[16];
    #pragma unroll
    for (int i = 0; i < 16; ++i) acc[i] = 0.f;
    for (int k0 = 0; k0 < D; k0 += 4) {
        float wv0 = W[(k0 + 0) * D + f];
        float wv1 = W[(k0 + 1) * D + f];
        float wv2 = W[(k0 + 2) * D + f];
        float wv3 = W[(k0 + 3) * D + f];
        #pragma unroll
        for (int i = 0; i < 16; ++i) {
            float4 av = *reinterpret_cast<const float4*>(&sA[sub + i * 2][k0]);
            acc[i] += av.x * wv0 + av.y * wv1 + av.z * wv2 + av.w * wv3;
        }
    }
    float alpha = a1[0];
    float bias = b[f];
    float s1 = 0.f, s2 = 0.f;
    #pragma unroll
    for (int i = 0; i < 16; ++i) {
        int node = n0 + sub + i * 2;
        if (node < nN) {
            float v = acc[i] + bias;
            v = v > 0.f ? v : alpha * v;
            agg[(size_t)node * D + f] = v;
            s1 += v;
            s2 += v * v;
        }
    }
    if (sub == 1) { r1[f] = s1; r2[f] = s2; }
    __syncthreads();
    if (sub == 0) {
        int slot = blockIdx.x & 15;
        atomicAdd(&sums[slot * D + f], s1 + r1[f]);
        atomicAdd(&sumsq[slot * D + f], s2 + r2[f]);
    }
}

__global__ void k_finalize(
        const float* __restrict__ sums, const float* __restrict__ sumsq,
        const float* __restrict__ gamma, const float* __restrict__ beta,
        float* __restrict__ stats, int nN) {
    int f = threadIdx.x;
    float s1 = 0.f, s2 = 0.f;
    #pragma unroll
    for (int i = 0; i < 16; ++i) { s1 += sums[i * D + f]; s2 += sumsq[i * D + f]; }
    float inv_n = 1.0f / (float)nN;
    float mean = s1 * inv_n;
    float var = s2 * inv_n - mean * mean;
    float inv = rsqrtf(var + 1e-5f);
    float sc = gamma[f] * inv;
    stats[f] = sc;
    stats[D + f] = beta[f] - mean * sc;
}

__global__ __launch_bounds__(256) void k_apply(
        float* __restrict__ h, const float* __restrict__ stats,
        const float* __restrict__ a2, int total4) {
    int i = blockIdx.x * 256 + threadIdx.x;
    if (i >= total4) return;
    float alpha = a2[0];
    int c = (i & 31) << 2;
    float4 v = *reinterpret_cast<const float4*>(h + (size_t)i * 4);
    float4 sc = *reinterpret_cast<const float4*>(stats + c);
    float4 sh = *reinterpret_cast<const float4*>(stats + D + c);
    float4 r;
    r.x = v.x * sc.x + sh.x; r.x = r.x > 0.f ? r.x : alpha * r.x;
    r.y = v.y * sc.y + sh.y; r.y = r.y > 0.f ? r.y : alpha * r.y;
    r.z = v.z * sc.z + sh.z; r.z = r.z > 0.f ? r.z : alpha * r.z;
    r.w = v.w * sc.w + sh.w; r.w = r.w > 0.f ? r.w : alpha * r.w;
    *reinterpret_cast<float4*>(h + (size_t)i * 4) = r;
}

extern "C" void kernel_launch(void* const* d_in, const int* in_sizes, int n_in,
                              void* d_out, int out_size, void* d_ws, size_t ws_size,
                              hipStream_t stream) {
    const float* heat  = (const float*)d_in[0];
    const float* W     = (const float*)d_in[1];
    const float* b     = (const float*)d_in[2];
    const float* a1    = (const float*)d_in[3];
    const float* gamma = (const float*)d_in[4];
    const float* beta  = (const float*)d_in[5];
    const float* a2    = (const float*)d_in[6];
    const int*   src   = (const int*)d_in[7];
    const int*   dst   = (const int*)d_in[8];

    const int nN = in_sizes[0] / D;
    const int nE = in_sizes[7];
    const int NB = (nN + 255) >> 8;            // dst buckets (391)
    const int nEB = (nE + 4095) / 4096;        // edge blocks

    char* ws = (char*)d_ws;
    size_t o = 0;
    auto alloc = [&](size_t bytes) { size_t r = o; o = (o + bytes + 255) & ~(size_t)255; return r; };
    int*   degO  = (int*)(ws + alloc((size_t)nN * 4));
    int*   bcnt  = (int*)(ws + alloc(512 * 4));
    int*   bbase = (int*)(ws + alloc(513 * 4));
    int*   bcur  = (int*)(ws + alloc(512 * 4));
    float* sums  = (float*)(ws + alloc(16 * D * 4));
    float* sumsq = (float*)(ws + alloc(16 * D * 4));
    size_t zero_end = o;                       // memset covers everything above
    float* stats = (float*)(ws + alloc(2 * D * 4));
    int*   degI  = (int*)(ws + alloc((size_t)nN * 4));
    int*   offs  = (int*)(ws + alloc((size_t)nN * 4));
    int*   elist = (int*)(ws + alloc((size_t)nE * 4));
    uint2* pairs = (uint2*)(ws + alloc((size_t)nE * 8));
    unsigned short* heatS = (unsigned short*)(ws + alloc((size_t)nN * D * 2));
    float* agg = (float*)d_out;                // agg / h / output share d_out

    hipMemsetAsync(ws, 0, zero_end, stream);

    k_count<<<nEB, 256, 0, stream>>>(src, dst, degO, bcnt, nE, NB);
    k_prep2<<<(nN * 32 + 255) / 256, 256, 0, stream>>>(heat, degO, heatS, nN);
    k_bscan<<<1, 512, 0, stream>>>(bcnt, bbase, bcur, NB);
    k_pairs<<<nEB, 256, 0, stream>>>(src, dst, bcur, pairs, nE, NB);
    k_binD<<<NB, 256, 0, stream>>>(pairs, bbase, degI, offs, elist, nN);
    k_gather<<<(nN + 3) / 4, 256, 0, stream>>>(heatS, elist, offs, degI, agg, nN);
    k_gemm<<<(nN + TN - 1) / TN, 256, 0, stream>>>(agg, W, b, degI, a1, sums, sumsq, nN);
    k_finalize<<<1, 128, 0, stream>>>(sums, sumsq, gamma, beta, stats, nN);
    k_apply<<<(nN * (D / 4) + 255) / 256, 256, 0, stream>>>(agg, stats, a2, nN * (D / 4));
}

// Round 5
// 276.591 us; speedup vs baseline: 10.5473x; 1.2262x over previous
//
#include <hip/hip_runtime.h>

#define D 128

__device__ __forceinline__ unsigned int f2bf(float x) {
    unsigned int u = __float_as_uint(x);
    return (u + 0x7FFFu + ((u >> 16) & 1u)) >> 16;   // RNE
}

// per-bucket dst histogram (bucket = dst>>8)
__global__ __launch_bounds__(256) void k_count(
        const int* __restrict__ dst, int* __restrict__ bcnt, int nE, int NB) {
    __shared__ int lh[512];
    int t = threadIdx.x;
    lh[t] = 0; lh[t + 256] = 0;
    __syncthreads();
    int base = blockIdx.x * 4096;
    #pragma unroll
    for (int i = 0; i < 16; ++i) {
        int e = base + i * 256 + t;
        if (e < nE) atomicAdd(&lh[dst[e] >> 8], 1);
    }
    __syncthreads();
    for (int i = t; i < NB; i += 256)
        if (lh[i]) atomicAdd(&bcnt[i], lh[i]);
}

// heatS = bf16(heat * rsqrt(max(degO,1)))
__global__ __launch_bounds__(256) void k_prep2(
        const float* __restrict__ heat, const int* __restrict__ degO,
        unsigned short* __restrict__ heatS, int nN) {
    int i = blockIdx.x * 256 + threadIdx.x;
    if (i >= nN * 32) return;
    int node = i >> 5;
    int c4 = (i & 31) << 2;
    float4 v = *reinterpret_cast<const float4*>(heat + ((size_t)node << 7) + c4);
    float sc = rsqrtf((float)max(degO[node], 1));
    unsigned int b0 = f2bf(v.x * sc), b1 = f2bf(v.y * sc);
    unsigned int b2 = f2bf(v.z * sc), b3 = f2bf(v.w * sc);
    uint2 p = make_uint2(b0 | (b1 << 16), b2 | (b3 << 16));
    *reinterpret_cast<uint2*>(heatS + ((size_t)node << 7) + c4) = p;
}

// exclusive scan of bucket counts (NB <= 512), one block
__global__ __launch_bounds__(512) void k_bscan(
        const int* __restrict__ bcnt, int* __restrict__ bbase,
        int* __restrict__ bcur, int NB) {
    __shared__ int sh[512];
    int t = threadIdx.x;
    sh[t] = (t < NB) ? bcnt[t] : 0;
    __syncthreads();
    for (int off = 1; off < 512; off <<= 1) {
        int u = (t >= off) ? sh[t - off] : 0;
        __syncthreads();
        sh[t] += u;
        __syncthreads();
    }
    int excl = (t == 0) ? 0 : sh[t - 1];
    if (t < NB) { bbase[t] = excl; bcur[t] = excl; }
    if (t == 511) bbase[NB] = sh[511];
}

// bin packed (src<<8 | dst&255) into bucket regions; also degO atomics
__global__ __launch_bounds__(256) void k_pairs(
        const int* __restrict__ src, const int* __restrict__ dst,
        int* __restrict__ degO, int* __restrict__ bcur,
        unsigned int* __restrict__ pairs, int nE, int NB) {
    __shared__ int lh[512];
    __shared__ int lcur[512];
    int t = threadIdx.x;
    lh[t] = 0; lh[t + 256] = 0;
    __syncthreads();
    int base = blockIdx.x * 4096;
    #pragma unroll
    for (int i = 0; i < 16; ++i) {
        int e = base + i * 256 + t;
        if (e < nE) atomicAdd(&lh[dst[e] >> 8], 1);
    }
    __syncthreads();
    for (int i = t; i < NB; i += 256) {
        int c = lh[i];
        lcur[i] = c ? atomicAdd(&bcur[i], c) : 0;
    }
    __syncthreads();
    #pragma unroll
    for (int i = 0; i < 16; ++i) {
        int e = base + i * 256 + t;
        if (e < nE) {
            int s = src[e], d = dst[e];
            atomicAdd(&degO[s], 1);
            int pos = atomicAdd(&lcur[d >> 8], 1);
            pairs[pos] = ((unsigned)s << 8) | (unsigned)(d & 255);
        }
    }
}

// per bucket: per-node counts -> degI/offs, grouped elist
__global__ __launch_bounds__(256) void k_binD(
        const unsigned int* __restrict__ pairs, const int* __restrict__ bbase,
        int* __restrict__ degI, int* __restrict__ offs,
        int* __restrict__ elist, int nN) {
    __shared__ int c0[256], sh[256], lcur[256];
    int b = blockIdx.x, t = threadIdx.x;
    int p0 = bbase[b], p1 = bbase[b + 1];
    int n0 = b << 8;
    c0[t] = 0;
    __syncthreads();
    for (int j = p0 + t; j < p1; j += 256)
        atomicAdd(&c0[pairs[j] & 255u], 1);
    __syncthreads();
    sh[t] = c0[t];
    __syncthreads();
    for (int off = 1; off < 256; off <<= 1) {
        int u = (t >= off) ? sh[t - off] : 0;
        __syncthreads();
        sh[t] += u;
        __syncthreads();
    }
    int excl = (t == 0) ? 0 : sh[t - 1];
    int node = n0 + t;
    if (node < nN) { degI[node] = c0[t]; offs[node] = p0 + excl; }
    lcur[t] = p0 + excl;
    __syncthreads();
    for (int j = p0 + t; j < p1; j += 256) {
        unsigned int pr = pairs[j];
        int pos = atomicAdd(&lcur[pr & 255u], 1);
        elist[pos] = (int)(pr >> 8);
    }
}

// one wave per node, 8-deep MLP: agg[node] = sum of pre-scaled bf16 neighbor rows
__global__ __launch_bounds__(256) void k_gather(
        const unsigned short* __restrict__ heatS, const int* __restrict__ elist,
        const int* __restrict__ offs, const int* __restrict__ degI,
        float* __restrict__ agg, int nN) {
    int node = blockIdx.x * 4 + (threadIdx.x >> 6);
    if (node >= nN) return;
    int l = threadIdx.x & 63;
    size_t col = (size_t)(l << 1);
    int start = offs[node];
    int end = start + degI[node];
    float ax = 0.f, ay = 0.f;
    for (int jb = start; jb < end; jb += 64) {
        int cnt = min(64, end - jb);
        int sl = (l < cnt) ? elist[jb + l] : 0;
        int k = 0;
        for (; k + 8 <= cnt; k += 8) {
            unsigned int p0, p1, p2, p3, p4, p5, p6, p7;
            {
                int s0 = __shfl(sl, k + 0), s1 = __shfl(sl, k + 1);
                int s2 = __shfl(sl, k + 2), s3 = __shfl(sl, k + 3);
                int s4 = __shfl(sl, k + 4), s5 = __shfl(sl, k + 5);
                int s6 = __shfl(sl, k + 6), s7 = __shfl(sl, k + 7);
                p0 = *reinterpret_cast<const unsigned int*>(heatS + ((size_t)s0 << 7) + col);
                p1 = *reinterpret_cast<const unsigned int*>(heatS + ((size_t)s1 << 7) + col);
                p2 = *reinterpret_cast<const unsigned int*>(heatS + ((size_t)s2 << 7) + col);
                p3 = *reinterpret_cast<const unsigned int*>(heatS + ((size_t)s3 << 7) + col);
                p4 = *reinterpret_cast<const unsigned int*>(heatS + ((size_t)s4 << 7) + col);
                p5 = *reinterpret_cast<const unsigned int*>(heatS + ((size_t)s5 << 7) + col);
                p6 = *reinterpret_cast<const unsigned int*>(heatS + ((size_t)s6 << 7) + col);
                p7 = *reinterpret_cast<const unsigned int*>(heatS + ((size_t)s7 << 7) + col);
            }
            ax += __uint_as_float(p0 << 16) + __uint_as_float(p1 << 16)
                + __uint_as_float(p2 << 16) + __uint_as_float(p3 << 16)
                + __uint_as_float(p4 << 16) + __uint_as_float(p5 << 16)
                + __uint_as_float(p6 << 16) + __uint_as_float(p7 << 16);
            ay += __uint_as_float(p0 & 0xFFFF0000u) + __uint_as_float(p1 & 0xFFFF0000u)
                + __uint_as_float(p2 & 0xFFFF0000u) + __uint_as_float(p3 & 0xFFFF0000u)
                + __uint_as_float(p4 & 0xFFFF0000u) + __uint_as_float(p5 & 0xFFFF0000u)
                + __uint_as_float(p6 & 0xFFFF0000u) + __uint_as_float(p7 & 0xFFFF0000u);
        }
        for (; k < cnt; ++k) {
            int s = __shfl(sl, k);
            unsigned int p = *reinterpret_cast<const unsigned int*>(heatS + ((size_t)s << 7) + col);
            ax += __uint_as_float(p << 16);
            ay += __uint_as_float(p & 0xFFFF0000u);
        }
    }
    *reinterpret_cast<float2*>(agg + ((size_t)node << 7) + (l << 1)) = make_float2(ax, ay);
}

// h = prelu( (agg * rsqrt(deg_in)) @ W + b, a1 );  in-place on d_out
// 2 features x 8 nodes per thread: halves LDS read traffic vs 1x16
#define TN 32
__global__ __launch_bounds__(256) void k_gemm(
        float* __restrict__ agg, const float* __restrict__ W,
        const float* __restrict__ b, const int* __restrict__ degI,
        const float* __restrict__ a1,
        float* __restrict__ sums, float* __restrict__ sumsq, int nN) {
    __shared__ float sA[TN][D + 4];
    __shared__ float r1[4][128], r2[4][128];
    int t = threadIdx.x;
    int n0 = blockIdx.x * TN;
    #pragma unroll
    for (int i = 0; i < 4; ++i) {
        int idx = t + i * 256;
        int n = idx >> 5;
        int c = (idx & 31) << 2;
        int node = n0 + n;
        float4 v = make_float4(0.f, 0.f, 0.f, 0.f);
        float sc = 0.f;
        if (node < nN) {
            v = *reinterpret_cast<const float4*>(agg + (size_t)node * D + c);
            sc = rsqrtf((float)max(degI[node], 1));
        }
        sA[n][c + 0] = v.x * sc;
        sA[n][c + 1] = v.y * sc;
        sA[n][c + 2] = v.z * sc;
        sA[n][c + 3] = v.w * sc;
    }
    __syncthreads();
    int fp = t & 63;            // features 2fp, 2fp+1
    int sub = t >> 6;           // nodes sub*8 + i  (wave-uniform -> LDS broadcast)
    float acc0[8], acc1[8];
    #pragma unroll
    for (int i = 0; i < 8; ++i) { acc0[i] = 0.f; acc1[i] = 0.f; }
    for (int k0 = 0; k0 < D; k0 += 4) {
        float2 w0 = *reinterpret_cast<const float2*>(W + (k0 + 0) * D + 2 * fp);
        float2 w1 = *reinterpret_cast<const float2*>(W + (k0 + 1) * D + 2 * fp);
        float2 w2 = *reinterpret_cast<const float2*>(W + (k0 + 2) * D + 2 * fp);
        float2 w3 = *reinterpret_cast<const float2*>(W + (k0 + 3) * D + 2 * fp);
        #pragma unroll
        for (int i = 0; i < 8; ++i) {
            float4 av = *reinterpret_cast<const float4*>(&sA[sub * 8 + i][k0]);
            acc0[i] += av.x * w0.x + av.y * w1.x + av.z * w2.x + av.w * w3.x;
            acc1[i] += av.x * w0.y + av.y * w1.y + av.z * w2.y + av.w * w3.y;
        }
    }
    float alpha = a1[0];
    float2 bias = *reinterpret_cast<const float2*>(b + 2 * fp);
    float s10 = 0.f, s20 = 0.f, s11 = 0.f, s21 = 0.f;
    #pragma unroll
    for (int i = 0; i < 8; ++i) {
        int node = n0 + sub * 8 + i;
        if (node < nN) {
            float v0 = acc0[i] + bias.x; v0 = v0 > 0.f ? v0 : alpha * v0;
            float v1 = acc1[i] + bias.y; v1 = v1 > 0.f ? v1 : alpha * v1;
            *reinterpret_cast<float2*>(agg + (size_t)node * D + 2 * fp) = make_float2(v0, v1);
            s10 += v0; s20 += v0 * v0;
            s11 += v1; s21 += v1 * v1;
        }
    }
    r1[sub][2 * fp] = s10; r1[sub][2 * fp + 1] = s11;
    r2[sub][2 * fp] = s20; r2[sub][2 * fp + 1] = s21;
    __syncthreads();
    if (t < 128) {
        float a = r1[0][t] + r1[1][t] + r1[2][t] + r1[3][t];
        float c = r2[0][t] + r2[1][t] + r2[2][t] + r2[3][t];
        int slot = blockIdx.x & 15;
        atomicAdd(&sums[slot * D + t], a);
        atomicAdd(&sumsq[slot * D + t], c);
    }
}

__global__ void k_finalize(
        const float* __restrict__ sums, const float* __restrict__ sumsq,
        const float* __restrict__ gamma, const float* __restrict__ beta,
        float* __restrict__ stats, int nN) {
    int f = threadIdx.x;
    float s1 = 0.f, s2 = 0.f;
    #pragma unroll
    for (int i = 0; i < 16; ++i) { s1 += sums[i * D + f]; s2 += sumsq[i * D + f]; }
    float inv_n = 1.0f / (float)nN;
    float mean = s1 * inv_n;
    float var = s2 * inv_n - mean * mean;
    float inv = rsqrtf(var + 1e-5f);
    float sc = gamma[f] * inv;
    stats[f] = sc;
    stats[D + f] = beta[f] - mean * sc;
}

__global__ __launch_bounds__(256) void k_apply(
        float* __restrict__ h, const float* __restrict__ stats,
        const float* __restrict__ a2, int total4) {
    int i = blockIdx.x * 256 + threadIdx.x;
    if (i >= total4) return;
    float alpha = a2[0];
    int c = (i & 31) << 2;
    float4 v = *reinterpret_cast<const float4*>(h + (size_t)i * 4);
    float4 sc = *reinterpret_cast<const float4*>(stats + c);
    float4 sh = *reinterpret_cast<const float4*>(stats + D + c);
    float4 r;
    r.x = v.x * sc.x + sh.x; r.x = r.x > 0.f ? r.x : alpha * r.x;
    r.y = v.y * sc.y + sh.y; r.y = r.y > 0.f ? r.y : alpha * r.y;
    r.z = v.z * sc.z + sh.z; r.z = r.z > 0.f ? r.z : alpha * r.z;
    r.w = v.w * sc.w + sh.w; r.w = r.w > 0.f ? r.w : alpha * r.w;
    *reinterpret_cast<float4*>(h + (size_t)i * 4) = r;
}

extern "C" void kernel_launch(void* const* d_in, const int* in_sizes, int n_in,
                              void* d_out, int out_size, void* d_ws, size_t ws_size,
                              hipStream_t stream) {
    const float* heat  = (const float*)d_in[0];
    const float* W     = (const float*)d_in[1];
    const float* b     = (const float*)d_in[2];
    const float* a1    = (const float*)d_in[3];
    const float* gamma = (const float*)d_in[4];
    const float* beta  = (const float*)d_in[5];
    const float* a2    = (const float*)d_in[6];
    const int*   src   = (const int*)d_in[7];
    const int*   dst   = (const int*)d_in[8];

    const int nN = in_sizes[0] / D;
    const int nE = in_sizes[7];
    const int NB = (nN + 255) >> 8;            // dst buckets (391)
    const int nEB = (nE + 4095) / 4096;        // edge blocks

    char* ws = (char*)d_ws;
    size_t o = 0;
    auto alloc = [&](size_t bytes) { size_t r = o; o = (o + bytes + 255) & ~(size_t)255; return r; };
    int*   degO  = (int*)(ws + alloc((size_t)nN * 4));
    int*   bcnt  = (int*)(ws + alloc(512 * 4));
    int*   bbase = (int*)(ws + alloc(513 * 4));
    int*   bcur  = (int*)(ws + alloc(512 * 4));
    float* sums  = (float*)(ws + alloc(16 * D * 4));
    float* sumsq = (float*)(ws + alloc(16 * D * 4));
    size_t zero_end = o;                       // memset covers everything above
    float* stats = (float*)(ws + alloc(2 * D * 4));
    int*   degI  = (int*)(ws + alloc((size_t)nN * 4));
    int*   offs  = (int*)(ws + alloc((size_t)nN * 4));
    int*   elist = (int*)(ws + alloc((size_t)nE * 4));
    unsigned int* pairs = (unsigned int*)(ws + alloc((size_t)nE * 4));
    unsigned short* heatS = (unsigned short*)(ws + alloc((size_t)nN * D * 2));
    float* agg = (float*)d_out;                // agg / h / output share d_out

    hipMemsetAsync(ws, 0, zero_end, stream);

    k_count<<<nEB, 256, 0, stream>>>(dst, bcnt, nE, NB);
    k_bscan<<<1, 512, 0, stream>>>(bcnt, bbase, bcur, NB);
    k_pairs<<<nEB, 256, 0, stream>>>(src, dst, degO, bcur, pairs, nE, NB);
    k_prep2<<<(nN * 32 + 255) / 256, 256, 0, stream>>>(heat, degO, heatS, nN);
    k_binD<<<NB, 256, 0, stream>>>(pairs, bbase, degI, offs, elist, nN);
    k_gather<<<(nN + 3) / 4, 256, 0, stream>>>(heatS, elist, offs, degI, agg, nN);
    k_gemm<<<(nN + TN - 1) / TN, 256, 0, stream>>>(agg, W, b, degI, a1, sums, sumsq, nN);
    k_finalize<<<1, 128, 0, stream>>>(sums, sumsq, gamma, beta, stats, nN);
    k_apply<<<(nN * (D / 4) + 255) / 256, 256, 0, stream>>>(agg, stats, a2, nN * (D / 4));
}

// Round 6
// 240.512 us; speedup vs baseline: 12.1295x; 1.1500x over previous
//
#include <hip/hip_runtime.h>

#define D 128
// 512-node buckets; requires nN <= 131072 (here 100000) and src < 2^23 for packing
#define BSH 9
#define BW 512

__device__ __forceinline__ unsigned int f2bf(float x) {
    unsigned int u = __float_as_uint(x);
    return (u + 0x7FFFu + ((u >> 16) & 1u)) >> 16;   // RNE
}

// per-bucket histograms of dst AND src (bucket = id>>9)
__global__ __launch_bounds__(256) void k_count(
        const int* __restrict__ src, const int* __restrict__ dst,
        int* __restrict__ bcntD, int* __restrict__ bcntS, int nE, int NBK) {
    __shared__ int lhD[256], lhS[256];
    int t = threadIdx.x;
    lhD[t] = 0; lhS[t] = 0;
    __syncthreads();
    int base = blockIdx.x * 4096;
    #pragma unroll
    for (int i = 0; i < 16; ++i) {
        int e = base + i * 256 + t;
        if (e < nE) {
            atomicAdd(&lhD[dst[e] >> BSH], 1);
            atomicAdd(&lhS[src[e] >> BSH], 1);
        }
    }
    __syncthreads();
    if (t < NBK) {
        if (lhD[t]) atomicAdd(&bcntD[t], lhD[t]);
        if (lhS[t]) atomicAdd(&bcntS[t], lhS[t]);
    }
}

// exclusive scan of both bucket-count arrays (NBK <= 256), one block
__global__ __launch_bounds__(256) void k_bscan2(
        const int* __restrict__ bcntD, const int* __restrict__ bcntS,
        int* __restrict__ bbaseD, int* __restrict__ bcurD,
        int* __restrict__ bbaseS, int* __restrict__ bcurS, int NBK, int nE) {
    __shared__ int sh[256];
    int t = threadIdx.x;
    // dst
    sh[t] = (t < NBK) ? bcntD[t] : 0;
    __syncthreads();
    for (int off = 1; off < 256; off <<= 1) {
        int u = (t >= off) ? sh[t - off] : 0;
        __syncthreads();
        sh[t] += u;
        __syncthreads();
    }
    if (t < NBK) {
        int excl = (t == 0) ? 0 : sh[t - 1];
        bbaseD[t] = excl; bcurD[t] = excl;
    }
    if (t == 0) bbaseD[NBK] = nE;
    __syncthreads();
    // src
    sh[t] = (t < NBK) ? bcntS[t] : 0;
    __syncthreads();
    for (int off = 1; off < 256; off <<= 1) {
        int u = (t >= off) ? sh[t - off] : 0;
        __syncthreads();
        sh[t] += u;
        __syncthreads();
    }
    if (t < NBK) {
        int excl = (t == 0) ? 0 : sh[t - 1];
        bbaseS[t] = excl; bcurS[t] = excl;
    }
    if (t == 0) bbaseS[NBK] = nE;
}

// bin packed (src<<9 | dst&511) by dst bucket, and u16(src&511) by src bucket
__global__ __launch_bounds__(256) void k_pairs(
        const int* __restrict__ src, const int* __restrict__ dst,
        int* __restrict__ bcurD, int* __restrict__ bcurS,
        unsigned int* __restrict__ pairsD, unsigned short* __restrict__ srcL,
        int nE) {
    __shared__ int lhD[256], lcD[256], lhS[256], lcS[256];
    int t = threadIdx.x;
    lhD[t] = 0; lhS[t] = 0;
    __syncthreads();
    int base = blockIdx.x * 4096;
    #pragma unroll
    for (int i = 0; i < 16; ++i) {
        int e = base + i * 256 + t;
        if (e < nE) {
            atomicAdd(&lhD[dst[e] >> BSH], 1);
            atomicAdd(&lhS[src[e] >> BSH], 1);
        }
    }
    __syncthreads();
    int cD = lhD[t];
    lcD[t] = cD ? atomicAdd(&bcurD[t], cD) : 0;
    int cS = lhS[t];
    lcS[t] = cS ? atomicAdd(&bcurS[t], cS) : 0;
    __syncthreads();
    #pragma unroll
    for (int i = 0; i < 16; ++i) {
        int e = base + i * 256 + t;
        if (e < nE) {
            int s = src[e], d = dst[e];
            int pD = atomicAdd(&lcD[d >> BSH], 1);
            pairsD[pD] = ((unsigned)s << BSH) | (unsigned)(d & (BW - 1));
            int pS = atomicAdd(&lcS[s >> BSH], 1);
            srcL[pS] = (unsigned short)(s & (BW - 1));
        }
    }
}

// per dst-bucket: per-node counts -> degI/offs, grouped elist
__global__ __launch_bounds__(512) void k_binD(
        const unsigned int* __restrict__ pairsD, const int* __restrict__ bbaseD,
        int* __restrict__ degI, int* __restrict__ offs,
        int* __restrict__ elist, int nN) {
    __shared__ int c0[BW], sh[BW], lcur[BW];
    int b = blockIdx.x, t = threadIdx.x;
    int p0 = bbaseD[b], p1 = bbaseD[b + 1];
    int n0 = b << BSH;
    c0[t] = 0;
    __syncthreads();
    for (int j = p0 + t; j < p1; j += 512)
        atomicAdd(&c0[pairsD[j] & (BW - 1u)], 1);
    __syncthreads();
    sh[t] = c0[t];
    __syncthreads();
    for (int off = 1; off < BW; off <<= 1) {
        int u = (t >= off) ? sh[t - off] : 0;
        __syncthreads();
        sh[t] += u;
        __syncthreads();
    }
    int excl = (t == 0) ? 0 : sh[t - 1];
    int node = n0 + t;
    if (node < nN) { degI[node] = c0[t]; offs[node] = p0 + excl; }
    lcur[t] = p0 + excl;
    __syncthreads();
    for (int j = p0 + t; j < p1; j += 512) {
        unsigned int pr = pairsD[j];
        int pos = atomicAdd(&lcur[pr & (BW - 1u)], 1);
        elist[pos] = (int)(pr >> BSH);
    }
}

// per src-bucket: per-node counts -> degO (writes every node in bucket)
__global__ __launch_bounds__(512) void k_binO(
        const unsigned short* __restrict__ srcL, const int* __restrict__ bbaseS,
        int* __restrict__ degO, int nN) {
    __shared__ int c0[BW];
    int b = blockIdx.x, t = threadIdx.x;
    int p0 = bbaseS[b], p1 = bbaseS[b + 1];
    c0[t] = 0;
    __syncthreads();
    for (int j = p0 + t; j < p1; j += 512)
        atomicAdd(&c0[srcL[j]], 1);
    __syncthreads();
    int node = (b << BSH) + t;
    if (node < nN) degO[node] = c0[t];
}

// heatS = bf16(heat * rsqrt(max(degO,1)))
__global__ __launch_bounds__(256) void k_prep2(
        const float* __restrict__ heat, const int* __restrict__ degO,
        unsigned short* __restrict__ heatS, int nN) {
    int i = blockIdx.x * 256 + threadIdx.x;
    if (i >= nN * 32) return;
    int node = i >> 5;
    int c4 = (i & 31) << 2;
    float4 v = *reinterpret_cast<const float4*>(heat + ((size_t)node << 7) + c4);
    float sc = rsqrtf((float)max(degO[node], 1));
    unsigned int b0 = f2bf(v.x * sc), b1 = f2bf(v.y * sc);
    unsigned int b2 = f2bf(v.z * sc), b3 = f2bf(v.w * sc);
    uint2 p = make_uint2(b0 | (b1 << 16), b2 | (b3 << 16));
    *reinterpret_cast<uint2*>(heatS + ((size_t)node << 7) + c4) = p;
}

// one wave per node, 8-deep MLP: agg[node] = sum of pre-scaled bf16 neighbor rows
__global__ __launch_bounds__(256) void k_gather(
        const unsigned short* __restrict__ heatS, const int* __restrict__ elist,
        const int* __restrict__ offs, const int* __restrict__ degI,
        float* __restrict__ agg, int nN) {
    int node = blockIdx.x * 4 + (threadIdx.x >> 6);
    if (node >= nN) return;
    int l = threadIdx.x & 63;
    size_t col = (size_t)(l << 1);
    int start = offs[node];
    int end = start + degI[node];
    float ax = 0.f, ay = 0.f;
    for (int jb = start; jb < end; jb += 64) {
        int cnt = min(64, end - jb);
        int sl = (l < cnt) ? elist[jb + l] : 0;
        int k = 0;
        for (; k + 8 <= cnt; k += 8) {
            unsigned int p0, p1, p2, p3, p4, p5, p6, p7;
            {
                int s0 = __shfl(sl, k + 0), s1 = __shfl(sl, k + 1);
                int s2 = __shfl(sl, k + 2), s3 = __shfl(sl, k + 3);
                int s4 = __shfl(sl, k + 4), s5 = __shfl(sl, k + 5);
                int s6 = __shfl(sl, k + 6), s7 = __shfl(sl, k + 7);
                p0 = *reinterpret_cast<const unsigned int*>(heatS + ((size_t)s0 << 7) + col);
                p1 = *reinterpret_cast<const unsigned int*>(heatS + ((size_t)s1 << 7) + col);
                p2 = *reinterpret_cast<const unsigned int*>(heatS + ((size_t)s2 << 7) + col);
                p3 = *reinterpret_cast<const unsigned int*>(heatS + ((size_t)s3 << 7) + col);
                p4 = *reinterpret_cast<const unsigned int*>(heatS + ((size_t)s4 << 7) + col);
                p5 = *reinterpret_cast<const unsigned int*>(heatS + ((size_t)s5 << 7) + col);
                p6 = *reinterpret_cast<const unsigned int*>(heatS + ((size_t)s6 << 7) + col);
                p7 = *reinterpret_cast<const unsigned int*>(heatS + ((size_t)s7 << 7) + col);
            }
            ax += __uint_as_float(p0 << 16) + __uint_as_float(p1 << 16)
                + __uint_as_float(p2 << 16) + __uint_as_float(p3 << 16)
                + __uint_as_float(p4 << 16) + __uint_as_float(p5 << 16)
                + __uint_as_float(p6 << 16) + __uint_as_float(p7 << 16);
            ay += __uint_as_float(p0 & 0xFFFF0000u) + __uint_as_float(p1 & 0xFFFF0000u)
                + __uint_as_float(p2 & 0xFFFF0000u) + __uint_as_float(p3 & 0xFFFF0000u)
                + __uint_as_float(p4 & 0xFFFF0000u) + __uint_as_float(p5 & 0xFFFF0000u)
                + __uint_as_float(p6 & 0xFFFF0000u) + __uint_as_float(p7 & 0xFFFF0000u);
        }
        for (; k < cnt; ++k) {
            int s = __shfl(sl, k);
            unsigned int p = *reinterpret_cast<const unsigned int*>(heatS + ((size_t)s << 7) + col);
            ax += __uint_as_float(p << 16);
            ay += __uint_as_float(p & 0xFFFF0000u);
        }
    }
    *reinterpret_cast<float2*>(agg + ((size_t)node << 7) + (l << 1)) = make_float2(ax, ay);
}

// h = prelu( (agg * rsqrt(deg_in)) @ W + b, a1 );  in-place on d_out
#define TN 32
__global__ __launch_bounds__(256) void k_gemm(
        float* __restrict__ agg, const float* __restrict__ W,
        const float* __restrict__ b, const int* __restrict__ degI,
        const float* __restrict__ a1,
        float* __restrict__ sums, float* __restrict__ sumsq, int nN) {
    __shared__ float sA[TN][D + 4];
    __shared__ float r1[4][128], r2[4][128];
    int t = threadIdx.x;
    int n0 = blockIdx.x * TN;
    #pragma unroll
    for (int i = 0; i < 4; ++i) {
        int idx = t + i * 256;
        int n = idx >> 5;
        int c = (idx & 31) << 2;
        int node = n0 + n;
        float4 v = make_float4(0.f, 0.f, 0.f, 0.f);
        float sc = 0.f;
        if (node < nN) {
            v = *reinterpret_cast<const float4*>(agg + (size_t)node * D + c);
            sc = rsqrtf((float)max(degI[node], 1));
        }
        sA[n][c + 0] = v.x * sc;
        sA[n][c + 1] = v.y * sc;
        sA[n][c + 2] = v.z * sc;
        sA[n][c + 3] = v.w * sc;
    }
    __syncthreads();
    int fp = t & 63;
    int sub = t >> 6;
    float acc0[8], acc1[8];
    #pragma unroll
    for (int i = 0; i < 8; ++i) { acc0[i] = 0.f; acc1[i] = 0.f; }
    for (int k0 = 0; k0 < D; k0 += 4) {
        float2 w0 = *reinterpret_cast<const float2*>(W + (k0 + 0) * D + 2 * fp);
        float2 w1 = *reinterpret_cast<const float2*>(W + (k0 + 1) * D + 2 * fp);
        float2 w2 = *reinterpret_cast<const float2*>(W + (k0 + 2) * D + 2 * fp);
        float2 w3 = *reinterpret_cast<const float2*>(W + (k0 + 3) * D + 2 * fp);
        #pragma unroll
        for (int i = 0; i < 8; ++i) {
            float4 av = *reinterpret_cast<const float4*>(&sA[sub * 8 + i][k0]);
            acc0[i] += av.x * w0.x + av.y * w1.x + av.z * w2.x + av.w * w3.x;
            acc1[i] += av.x * w0.y + av.y * w1.y + av.z * w2.y + av.w * w3.y;
        }
    }
    float alpha = a1[0];
    float2 bias = *reinterpret_cast<const float2*>(b + 2 * fp);
    float s10 = 0.f, s20 = 0.f, s11 = 0.f, s21 = 0.f;
    #pragma unroll
    for (int i = 0; i < 8; ++i) {
        int node = n0 + sub * 8 + i;
        if (node < nN) {
            float v0 = acc0[i] + bias.x; v0 = v0 > 0.f ? v0 : alpha * v0;
            float v1 = acc1[i] + bias.y; v1 = v1 > 0.f ? v1 : alpha * v1;
            *reinterpret_cast<float2*>(agg + (size_t)node * D + 2 * fp) = make_float2(v0, v1);
            s10 += v0; s20 += v0 * v0;
            s11 += v1; s21 += v1 * v1;
        }
    }
    r1[sub][2 * fp] = s10; r1[sub][2 * fp + 1] = s11;
    r2[sub][2 * fp] = s20; r2[sub][2 * fp + 1] = s21;
    __syncthreads();
    if (t < 128) {
        float a = r1[0][t] + r1[1][t] + r1[2][t] + r1[3][t];
        float c = r2[0][t] + r2[1][t] + r2[2][t] + r2[3][t];
        int slot = blockIdx.x & 15;
        atomicAdd(&sums[slot * D + t], a);
        atomicAdd(&sumsq[slot * D + t], c);
    }
}

__global__ void k_finalize(
        const float* __restrict__ sums, const float* __restrict__ sumsq,
        const float* __restrict__ gamma, const float* __restrict__ beta,
        float* __restrict__ stats, int nN) {
    int f = threadIdx.x;
    float s1 = 0.f, s2 = 0.f;
    #pragma unroll
    for (int i = 0; i < 16; ++i) { s1 += sums[i * D + f]; s2 += sumsq[i * D + f]; }
    float inv_n = 1.0f / (float)nN;
    float mean = s1 * inv_n;
    float var = s2 * inv_n - mean * mean;
    float inv = rsqrtf(var + 1e-5f);
    float sc = gamma[f] * inv;
    stats[f] = sc;
    stats[D + f] = beta[f] - mean * sc;
}

__global__ __launch_bounds__(256) void k_apply(
        float* __restrict__ h, const float* __restrict__ stats,
        const float* __restrict__ a2, int total4) {
    int i = blockIdx.x * 256 + threadIdx.x;
    if (i >= total4) return;
    float alpha = a2[0];
    int c = (i & 31) << 2;
    float4 v = *reinterpret_cast<const float4*>(h + (size_t)i * 4);
    float4 sc = *reinterpret_cast<const float4*>(stats + c);
    float4 sh = *reinterpret_cast<const float4*>(stats + D + c);
    float4 r;
    r.x = v.x * sc.x + sh.x; r.x = r.x > 0.f ? r.x : alpha * r.x;
    r.y = v.y * sc.y + sh.y; r.y = r.y > 0.f ? r.y : alpha * r.y;
    r.z = v.z * sc.z + sh.z; r.z = r.z > 0.f ? r.z : alpha * r.z;
    r.w = v.w * sc.w + sh.w; r.w = r.w > 0.f ? r.w : alpha * r.w;
    *reinterpret_cast<float4*>(h + (size_t)i * 4) = r;
}

extern "C" void kernel_launch(void* const* d_in, const int* in_sizes, int n_in,
                              void* d_out, int out_size, void* d_ws, size_t ws_size,
                              hipStream_t stream) {
    const float* heat  = (const float*)d_in[0];
    const float* W     = (const float*)d_in[1];
    const float* b     = (const float*)d_in[2];
    const float* a1    = (const float*)d_in[3];
    const float* gamma = (const float*)d_in[4];
    const float* beta  = (const float*)d_in[5];
    const float* a2    = (const float*)d_in[6];
    const int*   src   = (const int*)d_in[7];
    const int*   dst   = (const int*)d_in[8];

    const int nN = in_sizes[0] / D;
    const int nE = in_sizes[7];
    const int NBK = (nN + BW - 1) >> BSH;      // 512-node buckets (196)
    const int nEB = (nE + 4095) / 4096;        // edge blocks (391)

    char* ws = (char*)d_ws;
    size_t o = 0;
    auto alloc = [&](size_t bytes) { size_t r = o; o = (o + bytes + 255) & ~(size_t)255; return r; };
    int*   bcntD = (int*)(ws + alloc(256 * 4));
    int*   bcntS = (int*)(ws + alloc(256 * 4));
    float* sums  = (float*)(ws + alloc(16 * D * 4));
    float* sumsq = (float*)(ws + alloc(16 * D * 4));
    size_t zero_end = o;                       // memset covers only the above (~18 KB)
    int*   bbaseD = (int*)(ws + alloc(257 * 4));
    int*   bcurD  = (int*)(ws + alloc(256 * 4));
    int*   bbaseS = (int*)(ws + alloc(257 * 4));
    int*   bcurS  = (int*)(ws + alloc(256 * 4));
    float* stats  = (float*)(ws + alloc(2 * D * 4));
    int*   degO   = (int*)(ws + alloc((size_t)nN * 4));
    int*   degI   = (int*)(ws + alloc((size_t)nN * 4));
    int*   offs   = (int*)(ws + alloc((size_t)nN * 4));
    int*   elist  = (int*)(ws + alloc((size_t)nE * 4));
    unsigned int*   pairsD = (unsigned int*)(ws + alloc((size_t)nE * 4));
    unsigned short* srcL   = (unsigned short*)(ws + alloc((size_t)nE * 2));
    unsigned short* heatS  = (unsigned short*)(ws + alloc((size_t)nN * D * 2));
    float* agg = (float*)d_out;                // agg / h / output share d_out

    hipMemsetAsync(ws, 0, zero_end, stream);

    k_count<<<nEB, 256, 0, stream>>>(src, dst, bcntD, bcntS, nE, NBK);
    k_bscan2<<<1, 256, 0, stream>>>(bcntD, bcntS, bbaseD, bcurD, bbaseS, bcurS, NBK, nE);
    k_pairs<<<nEB, 256, 0, stream>>>(src, dst, bcurD, bcurS, pairsD, srcL, nE);
    k_binD<<<NBK, 512, 0, stream>>>(pairsD, bbaseD, degI, offs, elist, nN);
    k_binO<<<NBK, 512, 0, stream>>>(srcL, bbaseS, degO, nN);
    k_prep2<<<(nN * 32 + 255) / 256, 256, 0, stream>>>(heat, degO, heatS, nN);
    k_gather<<<(nN + 3) / 4, 256, 0, stream>>>(heatS, elist, offs, degI, agg, nN);
    k_gemm<<<(nN + TN - 1) / TN, 256, 0, stream>>>(agg, W, b, degI, a1, sums, sumsq, nN);
    k_finalize<<<1, 128, 0, stream>>>(sums, sumsq, gamma, beta, stats, nN);
    k_apply<<<(nN * (D / 4) + 255) / 256, 256, 0, stream>>>(agg, stats, a2, nN * (D / 4));
}

// Round 7
// 220.219 us; speedup vs baseline: 13.2472x; 1.0921x over previous
//
#include <hip/hip_runtime.h>

#define D 128
#define BSH 9
#define BW 512

typedef __attribute__((ext_vector_type(8))) short bf16x8;
typedef __attribute__((ext_vector_type(4))) float f32x4;

__device__ __forceinline__ unsigned int f2bf(float x) {
    unsigned int u = __float_as_uint(x);
    return (u + 0x7FFFu + ((u >> 16) & 1u)) >> 16;   // RNE
}

// per-bucket histograms of dst AND src (bucket = id>>9)
__global__ __launch_bounds__(256) void k_count(
        const int* __restrict__ src, const int* __restrict__ dst,
        int* __restrict__ bcntD, int* __restrict__ bcntS, int nE, int NBK) {
    __shared__ int lhD[256], lhS[256];
    int t = threadIdx.x;
    lhD[t] = 0; lhS[t] = 0;
    __syncthreads();
    int base = blockIdx.x * 4096;
    #pragma unroll
    for (int i = 0; i < 16; ++i) {
        int e = base + i * 256 + t;
        if (e < nE) {
            atomicAdd(&lhD[dst[e] >> BSH], 1);
            atomicAdd(&lhS[src[e] >> BSH], 1);
        }
    }
    __syncthreads();
    if (t < NBK) {
        if (lhD[t]) atomicAdd(&bcntD[t], lhD[t]);
        if (lhS[t]) atomicAdd(&bcntS[t], lhS[t]);
    }
}

__global__ __launch_bounds__(256) void k_bscan2(
        const int* __restrict__ bcntD, const int* __restrict__ bcntS,
        int* __restrict__ bbaseD, int* __restrict__ bcurD,
        int* __restrict__ bbaseS, int* __restrict__ bcurS, int NBK, int nE) {
    __shared__ int sh[256];
    int t = threadIdx.x;
    sh[t] = (t < NBK) ? bcntD[t] : 0;
    __syncthreads();
    for (int off = 1; off < 256; off <<= 1) {
        int u = (t >= off) ? sh[t - off] : 0;
        __syncthreads();
        sh[t] += u;
        __syncthreads();
    }
    if (t < NBK) {
        int excl = (t == 0) ? 0 : sh[t - 1];
        bbaseD[t] = excl; bcurD[t] = excl;
    }
    if (t == 0) bbaseD[NBK] = nE;
    __syncthreads();
    sh[t] = (t < NBK) ? bcntS[t] : 0;
    __syncthreads();
    for (int off = 1; off < 256; off <<= 1) {
        int u = (t >= off) ? sh[t - off] : 0;
        __syncthreads();
        sh[t] += u;
        __syncthreads();
    }
    if (t < NBK) {
        int excl = (t == 0) ? 0 : sh[t - 1];
        bbaseS[t] = excl; bcurS[t] = excl;
    }
    if (t == 0) bbaseS[NBK] = nE;
}

__global__ __launch_bounds__(256) void k_pairs(
        const int* __restrict__ src, const int* __restrict__ dst,
        int* __restrict__ bcurD, int* __restrict__ bcurS,
        unsigned int* __restrict__ pairsD, unsigned short* __restrict__ srcL,
        int nE) {
    __shared__ int lhD[256], lcD[256], lhS[256], lcS[256];
    int t = threadIdx.x;
    lhD[t] = 0; lhS[t] = 0;
    __syncthreads();
    int base = blockIdx.x * 4096;
    #pragma unroll
    for (int i = 0; i < 16; ++i) {
        int e = base + i * 256 + t;
        if (e < nE) {
            atomicAdd(&lhD[dst[e] >> BSH], 1);
            atomicAdd(&lhS[src[e] >> BSH], 1);
        }
    }
    __syncthreads();
    int cD = lhD[t];
    lcD[t] = cD ? atomicAdd(&bcurD[t], cD) : 0;
    int cS = lhS[t];
    lcS[t] = cS ? atomicAdd(&bcurS[t], cS) : 0;
    __syncthreads();
    #pragma unroll
    for (int i = 0; i < 16; ++i) {
        int e = base + i * 256 + t;
        if (e < nE) {
            int s = src[e], d = dst[e];
            int pD = atomicAdd(&lcD[d >> BSH], 1);
            pairsD[pD] = ((unsigned)s << BSH) | (unsigned)(d & (BW - 1));
            int pS = atomicAdd(&lcS[s >> BSH], 1);
            srcL[pS] = (unsigned short)(s & (BW - 1));
        }
    }
}

__global__ __launch_bounds__(512) void k_binD(
        const unsigned int* __restrict__ pairsD, const int* __restrict__ bbaseD,
        int* __restrict__ degI, int* __restrict__ offs,
        int* __restrict__ elist, int nN) {
    __shared__ int c0[BW], sh[BW], lcur[BW];
    int b = blockIdx.x, t = threadIdx.x;
    int p0 = bbaseD[b], p1 = bbaseD[b + 1];
    int n0 = b << BSH;
    c0[t] = 0;
    __syncthreads();
    for (int j = p0 + t; j < p1; j += 512)
        atomicAdd(&c0[pairsD[j] & (BW - 1u)], 1);
    __syncthreads();
    sh[t] = c0[t];
    __syncthreads();
    for (int off = 1; off < BW; off <<= 1) {
        int u = (t >= off) ? sh[t - off] : 0;
        __syncthreads();
        sh[t] += u;
        __syncthreads();
    }
    int excl = (t == 0) ? 0 : sh[t - 1];
    int node = n0 + t;
    if (node < nN) { degI[node] = c0[t]; offs[node] = p0 + excl; }
    lcur[t] = p0 + excl;
    __syncthreads();
    for (int j = p0 + t; j < p1; j += 512) {
        unsigned int pr = pairsD[j];
        int pos = atomicAdd(&lcur[pr & (BW - 1u)], 1);
        elist[pos] = (int)(pr >> BSH);
    }
}

__global__ __launch_bounds__(512) void k_binO(
        const unsigned short* __restrict__ srcL, const int* __restrict__ bbaseS,
        int* __restrict__ degO, int nN) {
    __shared__ int c0[BW];
    int b = blockIdx.x, t = threadIdx.x;
    int p0 = bbaseS[b], p1 = bbaseS[b + 1];
    c0[t] = 0;
    __syncthreads();
    for (int j = p0 + t; j < p1; j += 512)
        atomicAdd(&c0[srcL[j]], 1);
    __syncthreads();
    int node = (b << BSH) + t;
    if (node < nN) degO[node] = c0[t];
}

__global__ __launch_bounds__(256) void k_prep2(
        const float* __restrict__ heat, const int* __restrict__ degO,
        unsigned short* __restrict__ heatS, int nN) {
    int i = blockIdx.x * 256 + threadIdx.x;
    if (i >= nN * 32) return;
    int node = i >> 5;
    int c4 = (i & 31) << 2;
    float4 v = *reinterpret_cast<const float4*>(heat + ((size_t)node << 7) + c4);
    float sc = rsqrtf((float)max(degO[node], 1));
    unsigned int b0 = f2bf(v.x * sc), b1 = f2bf(v.y * sc);
    unsigned int b2 = f2bf(v.z * sc), b3 = f2bf(v.w * sc);
    uint2 p = make_uint2(b0 | (b1 << 16), b2 | (b3 << 16));
    *reinterpret_cast<uint2*>(heatS + ((size_t)node << 7) + c4) = p;
}

// W -> bf16, transposed: WtB[c*128 + k] = bf16(W[k*128 + c])
__global__ __launch_bounds__(256) void k_prepW(
        const float* __restrict__ W, unsigned short* __restrict__ WtB) {
    int idx = blockIdx.x * 256 + threadIdx.x;
    if (idx >= D * D) return;
    int k = idx >> 7, c = idx & 127;
    WtB[c * D + k] = (unsigned short)f2bf(W[idx]);
}

// one wave per node, 8-deep MLP; output bf16
__global__ __launch_bounds__(256) void k_gather(
        const unsigned short* __restrict__ heatS, const int* __restrict__ elist,
        const int* __restrict__ offs, const int* __restrict__ degI,
        unsigned int* __restrict__ aggB, int nN) {
    int node = blockIdx.x * 4 + (threadIdx.x >> 6);
    if (node >= nN) return;
    int l = threadIdx.x & 63;
    size_t col = (size_t)(l << 1);
    int start = offs[node];
    int end = start + degI[node];
    float ax = 0.f, ay = 0.f;
    for (int jb = start; jb < end; jb += 64) {
        int cnt = min(64, end - jb);
        int sl = (l < cnt) ? elist[jb + l] : 0;
        int k = 0;
        for (; k + 8 <= cnt; k += 8) {
            unsigned int p0, p1, p2, p3, p4, p5, p6, p7;
            {
                int s0 = __shfl(sl, k + 0), s1 = __shfl(sl, k + 1);
                int s2 = __shfl(sl, k + 2), s3 = __shfl(sl, k + 3);
                int s4 = __shfl(sl, k + 4), s5 = __shfl(sl, k + 5);
                int s6 = __shfl(sl, k + 6), s7 = __shfl(sl, k + 7);
                p0 = *reinterpret_cast<const unsigned int*>(heatS + ((size_t)s0 << 7) + col);
                p1 = *reinterpret_cast<const unsigned int*>(heatS + ((size_t)s1 << 7) + col);
                p2 = *reinterpret_cast<const unsigned int*>(heatS + ((size_t)s2 << 7) + col);
                p3 = *reinterpret_cast<const unsigned int*>(heatS + ((size_t)s3 << 7) + col);
                p4 = *reinterpret_cast<const unsigned int*>(heatS + ((size_t)s4 << 7) + col);
                p5 = *reinterpret_cast<const unsigned int*>(heatS + ((size_t)s5 << 7) + col);
                p6 = *reinterpret_cast<const unsigned int*>(heatS + ((size_t)s6 << 7) + col);
                p7 = *reinterpret_cast<const unsigned int*>(heatS + ((size_t)s7 << 7) + col);
            }
            ax += __uint_as_float(p0 << 16) + __uint_as_float(p1 << 16)
                + __uint_as_float(p2 << 16) + __uint_as_float(p3 << 16)
                + __uint_as_float(p4 << 16) + __uint_as_float(p5 << 16)
                + __uint_as_float(p6 << 16) + __uint_as_float(p7 << 16);
            ay += __uint_as_float(p0 & 0xFFFF0000u) + __uint_as_float(p1 & 0xFFFF0000u)
                + __uint_as_float(p2 & 0xFFFF0000u) + __uint_as_float(p3 & 0xFFFF0000u)
                + __uint_as_float(p4 & 0xFFFF0000u) + __uint_as_float(p5 & 0xFFFF0000u)
                + __uint_as_float(p6 & 0xFFFF0000u) + __uint_as_float(p7 & 0xFFFF0000u);
        }
        for (; k < cnt; ++k) {
            int s = __shfl(sl, k);
            unsigned int p = *reinterpret_cast<const unsigned int*>(heatS + ((size_t)s << 7) + col);
            ax += __uint_as_float(p << 16);
            ay += __uint_as_float(p & 0xFFFF0000u);
        }
    }
    aggB[((size_t)node << 6) + l] = f2bf(ax) | (f2bf(ay) << 16);
}

// MFMA gemm: h = prelu( rsqrt(degI) * (aggB @ W) + b , a1 ), stats
#define BM 64
__global__ __launch_bounds__(256) void k_gemm(
        const unsigned short* __restrict__ aggB, const unsigned short* __restrict__ WtB,
        const float* __restrict__ b, const int* __restrict__ degI,
        const float* __restrict__ a1, float* __restrict__ h,
        float* __restrict__ sums, float* __restrict__ sumsq, int nN) {
    __shared__ unsigned short sW[128 * 136];    // Wt padded: row c at c*136, 16B-aligned frags
    __shared__ float ss1[128], ss2[128];
    int t = threadIdx.x;
    {
        const unsigned int* Wu = (const unsigned int*)WtB;
        #pragma unroll
        for (int i = 0; i < 32; ++i) {
            int idx = t + i * 256;              // 8192 uints
            int c = idx >> 6;
            int kp = idx & 63;
            *(unsigned int*)&sW[c * 136 + kp * 2] = Wu[idx];
        }
    }
    if (t < 128) { ss1[t] = 0.f; ss2[t] = 0.f; }
    __syncthreads();

    int w = t >> 6;
    int l = t & 63;
    int lr = l & 15;        // A row-in-tile / B col-in-tile / C col
    int lq = l >> 4;        // k-group / C row-group
    int rowbase = blockIdx.x * BM + w * 16;

    f32x4 acc[8];
    #pragma unroll
    for (int ct = 0; ct < 8; ++ct) acc[ct] = (f32x4){0.f, 0.f, 0.f, 0.f};

    int arow = rowbase + lr;
    if (arow >= nN) arow = nN - 1;
    const unsigned short* arowp = aggB + ((size_t)arow << 7);

    #pragma unroll
    for (int ks = 0; ks < 4; ++ks) {
        bf16x8 afrag = *reinterpret_cast<const bf16x8*>(arowp + ks * 32 + lq * 8);
        #pragma unroll
        for (int ct = 0; ct < 8; ++ct) {
            bf16x8 bfrag = *reinterpret_cast<const bf16x8*>(
                &sW[(ct * 16 + lr) * 136 + ks * 32 + lq * 8]);
            acc[ct] = __builtin_amdgcn_mfma_f32_16x16x32_bf16(afrag, bfrag, acc[ct], 0, 0, 0);
        }
    }

    float alpha = a1[0];
    float s[4];
    int nv[4];
    #pragma unroll
    for (int j = 0; j < 4; ++j) {
        int n = rowbase + lq * 4 + j;
        nv[j] = n;
        s[j] = (n < nN) ? rsqrtf((float)max(degI[n], 1)) : 0.f;
    }
    #pragma unroll
    for (int ct = 0; ct < 8; ++ct) {
        int f = ct * 16 + lr;
        float bias = b[f];
        float p1 = 0.f, p2 = 0.f;
        #pragma unroll
        for (int j = 0; j < 4; ++j) {
            if (nv[j] < nN) {
                float v = acc[ct][j] * s[j] + bias;
                v = v > 0.f ? v : alpha * v;
                h[((size_t)nv[j] << 7) + f] = v;
                p1 += v; p2 += v * v;
            }
        }
        atomicAdd(&ss1[f], p1);
        atomicAdd(&ss2[f], p2);
    }
    __syncthreads();
    if (t < 128) {
        int slot = blockIdx.x & 15;
        atomicAdd(&sums[slot * D + t], ss1[t]);
        atomicAdd(&sumsq[slot * D + t], ss2[t]);
    }
}

__global__ void k_finalize(
        const float* __restrict__ sums, const float* __restrict__ sumsq,
        const float* __restrict__ gamma, const float* __restrict__ beta,
        float* __restrict__ stats, int nN) {
    int f = threadIdx.x;
    float s1 = 0.f, s2 = 0.f;
    #pragma unroll
    for (int i = 0; i < 16; ++i) { s1 += sums[i * D + f]; s2 += sumsq[i * D + f]; }
    float inv_n = 1.0f / (float)nN;
    float mean = s1 * inv_n;
    float var = s2 * inv_n - mean * mean;
    float inv = rsqrtf(var + 1e-5f);
    float sc = gamma[f] * inv;
    stats[f] = sc;
    stats[D + f] = beta[f] - mean * sc;
}

__global__ __launch_bounds__(256) void k_apply(
        float* __restrict__ h, const float* __restrict__ stats,
        const float* __restrict__ a2, int total4) {
    int i = blockIdx.x * 256 + threadIdx.x;
    if (i >= total4) return;
    float alpha = a2[0];
    int c = (i & 31) << 2;
    float4 v = *reinterpret_cast<const float4*>(h + (size_t)i * 4);
    float4 sc = *reinterpret_cast<const float4*>(stats + c);
    float4 sh = *reinterpret_cast<const float4*>(stats + D + c);
    float4 r;
    r.x = v.x * sc.x + sh.x; r.x = r.x > 0.f ? r.x : alpha * r.x;
    r.y = v.y * sc.y + sh.y; r.y = r.y > 0.f ? r.y : alpha * r.y;
    r.z = v.z * sc.z + sh.z; r.z = r.z > 0.f ? r.z : alpha * r.z;
    r.w = v.w * sc.w + sh.w; r.w = r.w > 0.f ? r.w : alpha * r.w;
    *reinterpret_cast<float4*>(h + (size_t)i * 4) = r;
}

extern "C" void kernel_launch(void* const* d_in, const int* in_sizes, int n_in,
                              void* d_out, int out_size, void* d_ws, size_t ws_size,
                              hipStream_t stream) {
    const float* heat  = (const float*)d_in[0];
    const float* W     = (const float*)d_in[1];
    const float* b     = (const float*)d_in[2];
    const float* a1    = (const float*)d_in[3];
    const float* gamma = (const float*)d_in[4];
    const float* beta  = (const float*)d_in[5];
    const float* a2    = (const float*)d_in[6];
    const int*   src   = (const int*)d_in[7];
    const int*   dst   = (const int*)d_in[8];

    const int nN = in_sizes[0] / D;
    const int nE = in_sizes[7];
    const int NBK = (nN + BW - 1) >> BSH;
    const int nEB = (nE + 4095) / 4096;

    char* ws = (char*)d_ws;
    size_t o = 0;
    auto alloc = [&](size_t bytes) { size_t r = o; o = (o + bytes + 255) & ~(size_t)255; return r; };
    int*   bcntD = (int*)(ws + alloc(256 * 4));
    int*   bcntS = (int*)(ws + alloc(256 * 4));
    float* sums  = (float*)(ws + alloc(16 * D * 4));
    float* sumsq = (float*)(ws + alloc(16 * D * 4));
    size_t zero_end = o;
    int*   bbaseD = (int*)(ws + alloc(257 * 4));
    int*   bcurD  = (int*)(ws + alloc(256 * 4));
    int*   bbaseS = (int*)(ws + alloc(257 * 4));
    int*   bcurS  = (int*)(ws + alloc(256 * 4));
    float* stats  = (float*)(ws + alloc(2 * D * 4));
    unsigned short* WtB = (unsigned short*)(ws + alloc((size_t)D * D * 2));
    int*   degO   = (int*)(ws + alloc((size_t)nN * 4));
    int*   degI   = (int*)(ws + alloc((size_t)nN * 4));
    int*   offs   = (int*)(ws + alloc((size_t)nN * 4));
    int*   elist  = (int*)(ws + alloc((size_t)nE * 4));
    unsigned short* heatS = (unsigned short*)(ws + alloc((size_t)nN * D * 2));
    // aliased region: pairsD+srcL are dead before gather writes aggB
    size_t alias0 = o;
    unsigned int*   pairsD = (unsigned int*)(ws + alloc((size_t)nE * 4));
    unsigned short* srcL   = (unsigned short*)(ws + alloc((size_t)nE * 2));
    unsigned int*   aggB   = (unsigned int*)(ws + alias0);   // nN*128 bf16 = 25.6 MB
    float* h = (float*)d_out;

    hipMemsetAsync(ws, 0, zero_end, stream);

    k_count<<<nEB, 256, 0, stream>>>(src, dst, bcntD, bcntS, nE, NBK);
    k_bscan2<<<1, 256, 0, stream>>>(bcntD, bcntS, bbaseD, bcurD, bbaseS, bcurS, NBK, nE);
    k_pairs<<<nEB, 256, 0, stream>>>(src, dst, bcurD, bcurS, pairsD, srcL, nE);
    k_binD<<<NBK, 512, 0, stream>>>(pairsD, bbaseD, degI, offs, elist, nN);
    k_binO<<<NBK, 512, 0, stream>>>(srcL, bbaseS, degO, nN);
    k_prepW<<<(D * D + 255) / 256, 256, 0, stream>>>(W, WtB);
    k_prep2<<<(nN * 32 + 255) / 256, 256, 0, stream>>>(heat, degO, heatS, nN);
    k_gather<<<(nN + 3) / 4, 256, 0, stream>>>(heatS, elist, offs, degI, aggB, nN);
    k_gemm<<<(nN + BM - 1) / BM, 256, 0, stream>>>(
        (const unsigned short*)aggB, WtB, b, degI, a1, h, sums, sumsq, nN);
    k_finalize<<<1, 128, 0, stream>>>(sums, sumsq, gamma, beta, stats, nN);
    k_apply<<<(nN * (D / 4) + 255) / 256, 256, 0, stream>>>(h, stats, a2, nN * (D / 4));
}